// Round 11
// baseline (1138.708 us; speedup 1.0000x reference)
//
#include <hip/hip_runtime.h>
#include <hip/hip_bf16.h>
#include <stdint.h>

#define SEQ    1024
#define NBAT   8
#define EMB    768
#define NHEAD  12
#define MROWS  (NBAT*SEQ)            // 8192
#define SCALE_S 0.03608439182435161f // 1/sqrt(768)

typedef unsigned short u16;
typedef __attribute__((ext_vector_type(8))) short bf16x8;
typedef __attribute__((ext_vector_type(4))) float f32x4;

typedef void __attribute__((address_space(1)))* gas_ptr;
typedef void __attribute__((address_space(3)))* las_ptr;

__device__ __forceinline__ void gload16(const void* g, void* l) {
  __builtin_amdgcn_global_load_lds((gas_ptr)(void*)g, (las_ptr)l, 16, 0, 0);
}

#define VMCNT0 asm volatile("s_waitcnt vmcnt(0)" ::: "memory")
#define VMCNT2 asm volatile("s_waitcnt vmcnt(2)" ::: "memory")
#define VMCNT4 asm volatile("s_waitcnt vmcnt(4)" ::: "memory")
#define VMCNT6 asm volatile("s_waitcnt vmcnt(6)" ::: "memory")
#define LGKM0  asm volatile("s_waitcnt lgkmcnt(0)" ::: "memory")
#define BARRIER asm volatile("s_barrier" ::: "memory")

__device__ __forceinline__ u16 f2bf(float f) {
  union { float f; uint32_t u; } a; a.f = f;
  uint32_t r = a.u + 0x7fffu + ((a.u >> 16) & 1u);
  return (u16)(r >> 16);
}
__device__ __forceinline__ float bf2f(u16 b) {
  union { uint32_t u; float f; } c; c.u = (uint32_t)b << 16; return c.f;
}
__device__ __forceinline__ uint32_t pack2(float a, float b) {
  return (uint32_t)f2bf(a) | ((uint32_t)f2bf(b) << 16);
}

// ---------------- conversion / prep kernels ----------------
__global__ void k_cvt(const float* __restrict__ s, u16* __restrict__ d, long n) {
  long i = ((long)blockIdx.x*blockDim.x + threadIdx.x)*8;
  if (i >= n) return;
  float4 a = *(const float4*)(s+i);
  float4 b = *(const float4*)(s+i+4);
  uint4 o; o.x = pack2(a.x,a.y); o.y = pack2(a.z,a.w);
  o.z = pack2(b.x,b.y); o.w = pack2(b.z,b.w);
  *(uint4*)(d+i) = o;
}

// transpose-convert: f32 [768][768] (row=d) -> bf16 [768][768] (row=e)
__global__ void k_cvtT(const float* __restrict__ wq, const float* __restrict__ wk,
                       u16* __restrict__ dq, u16* __restrict__ dk, int Gi) {
  __shared__ float t[64][65];
  int z = blockIdx.z;
  const float* src = (z < Gi) ? wq + (size_t)z*EMB*EMB : wk + (size_t)(z-Gi)*EMB*EMB;
  u16* dst = (z < Gi) ? dq + (size_t)z*EMB*EMB : dk + (size_t)(z-Gi)*EMB*EMB;
  int d0 = blockIdx.x*64, e0 = blockIdx.y*64;
  int tt = threadIdx.x;
  int el = tt & 63, db = tt >> 6;
  #pragma unroll
  for (int p = 0; p < 16; ++p) {
    int dl = p*4 + db;
    t[dl][el] = src[(size_t)(d0+dl)*EMB + e0 + el];
  }
  __syncthreads();
  int dl2 = tt & 63, eb = tt >> 6;
  #pragma unroll
  for (int p = 0; p < 16; ++p) {
    int e2 = p*4 + eb;
    dst[(size_t)(e0+e2)*EMB + d0 + dl2] = f2bf(t[dl2][e2]);
  }
}

// convert full Wc [768, 9216] -> bf16
__global__ void k_cvtwc(const float* __restrict__ wc, u16* __restrict__ d, int Gi, int h0) {
  long ncol = (long)Gi*EMB;
  long i = ((long)blockIdx.x*blockDim.x + threadIdx.x)*4;
  if (i >= 768*ncol) return;
  long eo = i / ncol, c = i - eo*ncol;
  long g = c / EMB, dd = c - g*EMB;
  const float* s = wc + eo*(long)(NHEAD*EMB) + (h0+g)*EMB + dd;
  float4 a = *(const float4*)s;
  uint2 o; o.x = pack2(a.x,a.y); o.y = pack2(a.z,a.w);
  *(uint2*)(d+i) = o;
}

// a[g][e] = sum_d Wk[d][e]*bq[d]   (wkT row-major [e][d])
__global__ void k_mka(const u16* __restrict__ wkT, const float* __restrict__ bq,
                      float* __restrict__ a) {
  int g = blockIdx.y;
  int e = blockIdx.x*256 + threadIdx.x;
  const u16* row = wkT + (size_t)g*EMB*EMB + (size_t)e*EMB;
  const float* b = bq + (size_t)g*EMB;
  float s = 0.f;
  for (int d = 0; d < EMB; ++d) s += bf2f(row[d]) * b[d];
  a[(size_t)g*EMB + e] = s;
}

// v[g][i] = sum_e xb[i][e]*a[g][e]   (wave per row)
__global__ void k_mkv(const u16* __restrict__ xb, const float* __restrict__ a,
                      float* __restrict__ v) {
  int g = blockIdx.y;
  int w = threadIdx.x >> 6, l = threadIdx.x & 63;
  int i = blockIdx.x*8 + w;
  const u16* xr = xb + (size_t)i*EMB;
  const float* ag = a + (size_t)g*EMB;
  float s = 0.f;
  #pragma unroll
  for (int c = 0; c < 12; ++c) {
    int e = c*64 + l;
    s += bf2f(xr[e]) * ag[e];
  }
  s += __shfl_xor(s, 1); s += __shfl_xor(s, 2); s += __shfl_xor(s, 4);
  s += __shfl_xor(s, 8); s += __shfl_xor(s, 16); s += __shfl_xor(s, 32);
  if (l == 0) v[(size_t)g*MROWS + i] = s;
}

// ---------------- dual 256x256 NT GEMM (r4 structure; two configs per launch) ----------------
struct Gemm256Args {
  const u16* A; int lda;
  const u16* B; int ldb; int K;
  u16* Cb; long c_hs; int ldc;
  const float* bias; const float* bias2;
  int gsplit; int mode; int swap;
};

__global__ __launch_bounds__(512, 2) void k_gemm256d(Gemm256Args p0, Gemm256Args p1)
{
  __shared__ u16 lsA[2*16384];
  __shared__ u16 lsB[2*16384];

  const Gemm256Args P = blockIdx.z ? p1 : p0;
  int m0 = (P.swap ? blockIdx.y : blockIdx.x) * 256;
  int n0 = (P.swap ? blockIdx.x : blockIdx.y) * 256;
  int tid = threadIdx.x;
  int w = tid >> 6, l = tid & 63;
  int wr = w >> 2, wc = w & 3;

  const u16* gA = P.A + (size_t)(m0 + 32*w + (l>>3))*P.lda + (((l&7) ^ (l>>3)) << 3);
  const u16* gB = P.B + (size_t)(n0 + 32*w + (l>>3))*P.ldb + (((l&7) ^ (l>>3)) << 3);

#define STAGE256(t, buf) do { \
    int k0_ = (t)*64; \
    _Pragma("unroll") \
    for (int c_ = 0; c_ < 4; ++c_) \
      gload16(gA + (size_t)(c_*8)*P.lda + k0_, lsA + (buf)*16384 + (32*w + 8*c_)*64); \
    _Pragma("unroll") \
    for (int c_ = 0; c_ < 4; ++c_) \
      gload16(gB + (size_t)(c_*8)*P.ldb + k0_, lsB + (buf)*16384 + (32*w + 8*c_)*64); \
  } while(0)

  f32x4 acc[8][4];
  #pragma unroll
  for (int i = 0; i < 8; ++i)
    #pragma unroll
    for (int j = 0; j < 4; ++j) acc[i][j] = (f32x4)0.0f;

  int nt = P.K >> 6;
  STAGE256(0, 0);
  for (int t = 0; t < nt; ++t) {
    VMCNT0; BARRIER;
    if (t + 1 < nt) STAGE256(t+1, (t+1)&1);
    const u16* la = lsA + (t&1)*16384;
    const u16* lb = lsB + (t&1)*16384;
    #pragma unroll
    for (int ks = 0; ks < 2; ++ks) {
      int off = (((4*ks + (l>>4)) ^ (l&7)) << 3);
      bf16x8 af[8], bf_[4];
      #pragma unroll
      for (int fi = 0; fi < 8; ++fi)
        af[fi] = *(const bf16x8*)(la + (wr*128 + fi*16 + (l&15))*64 + off);
      #pragma unroll
      for (int fj = 0; fj < 4; ++fj)
        bf_[fj] = *(const bf16x8*)(lb + (wc*64 + fj*16 + (l&15))*64 + off);
      __builtin_amdgcn_s_setprio(1);
      #pragma unroll
      for (int fi = 0; fi < 8; ++fi)
        #pragma unroll
        for (int fj = 0; fj < 4; ++fj)
          acc[fi][fj] = __builtin_amdgcn_mfma_f32_16x16x32_bf16(af[fi], bf_[fj], acc[fi][fj], 0, 0, 0);
      __builtin_amdgcn_s_setprio(0);
    }
  }
#undef STAGE256

  if (P.mode == 0) {
    int s = n0 / 768;
    int dbase = n0 - s*768 + wc*64;
    const float* bsl = P.bias ? ((s < P.gsplit) ? P.bias + (size_t)s*768
                                                : P.bias2 + (size_t)(s - P.gsplit)*768)
                              : (const float*)0;
    u16* Cs = P.Cb + (size_t)s*P.c_hs;
    #pragma unroll
    for (int fj = 0; fj < 4; ++fj) {
      int dcol = dbase + fj*16 + (l&15);
      float bb = bsl ? bsl[dcol] : 0.f;
      #pragma unroll
      for (int fi = 0; fi < 8; ++fi) {
        #pragma unroll
        for (int r = 0; r < 4; ++r) {
          int row = m0 + wr*128 + fi*16 + (l>>4)*4 + r;
          Cs[(size_t)row*768 + dcol] = f2bf(acc[fi][fj][r] + bb);
        }
      }
    }
  } else {
    #pragma unroll
    for (int fi = 0; fi < 8; ++fi) {
      #pragma unroll
      for (int r = 0; r < 4; ++r) {
        int row = m0 + wr*128 + fi*16 + (l>>4)*4 + r;
        float bb = P.bias[row];
        #pragma unroll
        for (int fj = 0; fj < 4; ++fj) {
          int cbn = n0 + wc*64 + fj*16 + (l&15);
          P.Cb[(size_t)row*P.ldc + cbn] = f2bf(acc[fi][fj][r] + bb);
        }
      }
    }
  }
}

// ---------------- NT GEMM: 128x128 tile (Mt + output projection) ----------------
__global__ __launch_bounds__(256) void k_gemm(
    const u16* __restrict__ A, long a_hs, int lda,
    const u16* __restrict__ B, long b_hs, int ldb, int K,
    u16* Cb, float* Cf, long c_hs, int ldc,
    const float* __restrict__ bias, const float* __restrict__ bias2,
    long bias_hs, int gsplit, int mode, int swapxy)
{
  __shared__ u16 lsA[3*4096];
  __shared__ u16 lsB[3*4096];
  int g = blockIdx.z;
  const u16* Ag = A + (long)g*a_hs;
  const u16* Bg = B + (long)g*b_hs;
  int tm = swapxy ? blockIdx.y : blockIdx.x;
  int tn = swapxy ? blockIdx.x : blockIdx.y;
  int m0 = tm*128, n0 = tn*128;
  int tid = threadIdx.x;
  int w = tid >> 6, l = tid & 63;

  int srow = l >> 2;
  int scol = ((l & 3) ^ ((l >> 3) & 3)) * 8;
  const u16* ga0 = Ag + (long)(m0 + (2*w)*16   + srow)*lda + scol;
  const u16* ga1 = Ag + (long)(m0 + (2*w+1)*16 + srow)*lda + scol;
  const u16* gb0 = Bg + (long)(n0 + (2*w)*16   + srow)*ldb + scol;
  const u16* gb1 = Bg + (long)(n0 + (2*w+1)*16 + srow)*ldb + scol;

#define GSTAGE(k0, buf) do { \
    gload16(ga0 + (k0), lsA + (buf)*4096 + (2*w)*512); \
    gload16(ga1 + (k0), lsA + (buf)*4096 + (2*w+1)*512); \
    gload16(gb0 + (k0), lsB + (buf)*4096 + (2*w)*512); \
    gload16(gb1 + (k0), lsB + (buf)*4096 + (2*w+1)*512); \
  } while(0)

  f32x4 acc[4][4];
  #pragma unroll
  for (int i = 0; i < 4; ++i)
    #pragma unroll
    for (int j = 0; j < 4; ++j) acc[i][j] = (f32x4)0.0f;

  int wr = w >> 1, wc_ = w & 1;
  int frow = l & 15;
  int sp = (l >> 4) ^ ((frow >> 1) & 3);
  int aoff[4], boff[4];
  #pragma unroll
  for (int i = 0; i < 4; ++i) {
    aoff[i] = (wr*64 + i*16 + frow)*32 + sp*8;
    boff[i] = (wc_*64 + i*16 + frow)*32 + sp*8;
  }

  int nt = K >> 5;
  GSTAGE(0, 0);
  GSTAGE(32, 1);
  VMCNT4; BARRIER;
  int cur = 0;
  for (int t = 0; t < nt; ++t) {
    if (t + 2 < nt) {
      int nb = cur + 2; if (nb >= 3) nb -= 3;
      GSTAGE((t+2) << 5, nb);
    }
    const u16* la = lsA + cur*4096;
    const u16* lb = lsB + cur*4096;
    bf16x8 af[4], bfr[4];
    #pragma unroll
    for (int i = 0; i < 4; ++i) af[i] = *(const bf16x8*)(la + aoff[i]);
    #pragma unroll
    for (int j = 0; j < 4; ++j) bfr[j] = *(const bf16x8*)(lb + boff[j]);
    #pragma unroll
    for (int i = 0; i < 4; ++i)
      #pragma unroll
      for (int j = 0; j < 4; ++j)
        acc[i][j] = __builtin_amdgcn_mfma_f32_16x16x32_bf16(af[i], bfr[j], acc[i][j], 0, 0, 0);
    if (t + 2 < nt) { VMCNT4; } else { VMCNT0; }
    LGKM0; BARRIER;
    cur = (cur == 2) ? 0 : cur + 1;
  }
#undef GSTAGE

  u16* Cbg = Cb ? Cb + (long)g*c_hs : (u16*)0;
  const float* bsel = (g < gsplit) ? bias : bias2;
  long gi = (g < gsplit) ? g : g - gsplit;
  const float* bs = bsel ? bsel + gi*bias_hs : (const float*)0;
  int rl = (l >> 4)*4, cl = l & 15;
  #pragma unroll
  for (int i = 0; i < 4; ++i) {
    #pragma unroll
    for (int j = 0; j < 4; ++j) {
      int rb = m0 + wr*64 + i*16 + rl;
      int cb = n0 + wc_*64 + j*16 + cl;
      float cbv = 0.f;
      if ((mode == 0 || mode == 2) && bs) cbv = bs[cb];
      #pragma unroll
      for (int r = 0; r < 4; ++r) {
        int rr = rb + r;
        float v = acc[i][j][r];
        v += (mode == 1) ? bs[rr] : cbv;
        size_t idx = (size_t)rr*(size_t)ldc + cb;
        if (mode <= 1) Cbg[idx] = f2bf(v);
        else if (mode == 2) Cf[idx] = v;
        else Cf[idx] += v;
      }
    }
  }
}

// ---------------- flash attention (causal), QBLK=32, KBLK=64, 4 waves, 2 blocks/CU ----
// Per-wave structure identical to r8 (qg in {0,1}); 2-buf K + 2-buf V single-ahead
// pipeline; second resident block provides TLP to cover vmcnt drains.
// K-operand = xb shared across heads; per-key bias vh.
__global__ __launch_bounds__(256, 2) void k_attn(
    const u16* __restrict__ qb, const u16* __restrict__ xkb,
    const u16* __restrict__ vtb, const float* __restrict__ vh,
    u16* __restrict__ hb, int ldh)
{
  __shared__ u16 kls[2*8192];     // 2 bufs x 16KB (K chunks [64 k][128 e])
  __shared__ u16 vls[2*8192];     // 2 bufs x 16KB (V chunks [128 e][64 t])
  __shared__ float s_t[32*68];
  __shared__ u16 p_t[32*64];
  __shared__ float e_s[32];

  int b = blockIdx.x;
  int xcd = b & 7, kk_ = b >> 3;
  int pair = kk_ & 15;
  int gn = xcd + 8*(kk_ >> 4);
  int g = gn >> 3, n = gn & 7;

  const u16* Q  = qb  + (size_t)g*MROWS*EMB + (size_t)n*SEQ*EMB;
  const u16* Kp = xkb + (size_t)n*SEQ*EMB;
  const u16* Vt = vtb + (size_t)g*EMB*MROWS + (size_t)n*SEQ;
  const float* Vh = vh + (size_t)g*MROWS + (size_t)n*SEQ;
  u16* H = hb + (size_t)(n*SEQ)*ldh + (size_t)g*EMB;

  int tid = threadIdx.x;
  int w = tid >> 6, l = tid & 63;
  int qg = w >> 1;                 // q 16-row group (0..1)
  int cg = w & 1;                  // k/e column half
  int frow = l & 15;
  int fsw = frow & 7;
  int hi = l >> 4;
  int srow = tid >> 3;             // 0..31
  int sphys = tid & 7;
  int scol = ((sphys ^ (srow & 7)) << 3);

  // K chunk [2 k2][64 rows -> rows 0..63 via srow/srow+32][8 slots][8e]
#define KSTAGE(base, pc, buf) do { \
    const u16* s_ = (base) + (size_t)srow*EMB + (pc)*128 + scol; \
    u16* d_ = kls + (buf)*8192 + w*512; \
    gload16(s_,                  d_); \
    gload16(s_ + (size_t)32*EMB, d_ + 2048); \
    gload16(s_ + 64,                  d_ + 4096); \
    gload16(s_ + (size_t)32*EMB + 64, d_ + 6144); \
  } while(0)
  // V chunk [128 e][8 slots][8 t]
#define VSTAGE(vc, buf) do { \
    const u16* s_ = Vt + (size_t)((vc)*128 + srow)*MROWS + t0 + scol; \
    u16* d_ = vls + (buf)*8192 + w*512; \
    gload16(s_,                       d_); \
    gload16(s_ + (size_t)32*MROWS,    d_ + 2048); \
    gload16(s_ + (size_t)64*MROWS,    d_ + 4096); \
    gload16(s_ + (size_t)96*MROWS,    d_ + 6144); \
  } while(0)
  // Q chunk (8KB = [2 k2][32 rows][64 e])
#define QSTAGE(pc, dst) do { \
    const u16* s_ = Q + (size_t)(q0 + srow)*EMB + (pc)*128 + scol; \
    gload16(s_,      (dst) + w*512); \
    gload16(s_ + 64, (dst) + 2048 + w*512); \
  } while(0)
#define RD_Q(pc, src) do { \
    _Pragma("unroll") for (int kk2 = 0; kk2 < 2; ++kk2) \
      _Pragma("unroll") for (int kkl = 0; kkl < 2; ++kkl) \
        qreg[2*(pc) + kk2][kkl] = *(const bf16x8*)((src) + kk2*2048 + (qg*16 + frow)*64 \
                                                   + (((kkl*4 + hi) ^ fsw) << 3)); \
  } while(0)
#define QK_PH(c, buf) do { \
    const u16* kb_ = kls + (buf)*8192; \
    __builtin_amdgcn_s_setprio(1); \
    _Pragma("unroll") for (int kk2 = 0; kk2 < 2; ++kk2) \
      _Pragma("unroll") for (int kkl = 0; kkl < 2; ++kkl) { \
        int so = ((kkl*4 + hi) ^ fsw) << 3; \
        bf16x8 aq = qreg[2*(c) + kk2][kkl]; \
        _Pragma("unroll") for (int cc = 0; cc < 2; ++cc) { \
          bf16x8 bk_ = *(const bf16x8*)(kb_ + kk2*4096 + ((cg*2 + cc)*16 + frow)*64 + so); \
          sacc[cc] = __builtin_amdgcn_mfma_f32_16x16x32_bf16(aq, bk_, sacc[cc], 0, 0, 0); \
        } \
      } \
    __builtin_amdgcn_s_setprio(0); \
  } while(0)
#define PV_PH(c, buf) do { \
    const u16* vb_ = vls + (buf)*8192; \
    __builtin_amdgcn_s_setprio(1); \
    _Pragma("unroll") for (int cf = 0; cf < 4; ++cf) \
      _Pragma("unroll") for (int kk = 0; kk < 2; ++kk) { \
        bf16x8 vbf = *(const bf16x8*)(vb_ + (cg*64 + cf*16 + frow)*64 + (((kk*4 + hi) ^ fsw) << 3)); \
        acc[(c)][cf] = __builtin_amdgcn_mfma_f32_16x16x32_bf16(pa[kk], vbf, acc[(c)][cf], 0, 0, 0); \
      } \
    __builtin_amdgcn_s_setprio(0); \
  } while(0)

  for (int half = 0; half < 2; ++half) {
    int qt = half ? 31 - pair : pair;
    int q0 = qt * 32;
    int ntk = (qt >> 1) + 1;
    int qglob = q0 + srow;

    f32x4 acc[6][4];
    #pragma unroll
    for (int i = 0; i < 6; ++i)
      #pragma unroll
      for (int j = 0; j < 4; ++j) acc[i][j] = (f32x4)0.0f;
    float m_reg = -1e30f, l_reg = 0.f;

    // ---- prologue: Q -> qreg[24] through 4 bufs (kls0,kls1,vls0,vls1) ----
    bf16x8 qreg[12][2];
    VMCNT0;
    QSTAGE(0, kls); QSTAGE(1, kls + 8192); QSTAGE(2, vls); QSTAGE(3, vls + 8192);
    VMCNT6; BARRIER;
    RD_Q(0, kls);          VMCNT4; LGKM0; BARRIER;
    QSTAGE(4, kls);        RD_Q(1, kls + 8192); VMCNT4; LGKM0; BARRIER;
    QSTAGE(5, kls + 8192); RD_Q(2, vls);        VMCNT4; LGKM0; BARRIER;
    RD_Q(3, vls + 8192);   VMCNT2; LGKM0; BARRIER;
    RD_Q(4, kls);          VMCNT0; LGKM0; BARRIER;
    KSTAGE(Kp, 0, 0);      RD_Q(5, kls + 8192); VMCNT0; LGKM0; BARRIER;
    // state: K ch0 ready in kls0

    for (int tt = 0; tt < ntk; ++tt) {
      int t0 = tt*64;
      const u16* Kb  = Kp + (size_t)t0*EMB;
      const u16* Kbn = Kp + (size_t)(t0 + 64)*EMB;
      bool sn = (tt + 1 < ntk);
      float vv0 = Vh[t0 + cg*32 + frow];
      float vv1 = Vh[t0 + cg*32 + 16 + frow];

      f32x4 sacc[2]; sacc[0] = (f32x4)0.0f; sacc[1] = (f32x4)0.0f;
      // QK phases: {stage next; compute cur; vmcnt0; barrier}
      KSTAGE(Kb, 1, 1);  QK_PH(0, 0);  VMCNT0; BARRIER;
      KSTAGE(Kb, 2, 0);  QK_PH(1, 1);  VMCNT0; BARRIER;
      KSTAGE(Kb, 3, 1);  QK_PH(2, 0);  VMCNT0; BARRIER;
      KSTAGE(Kb, 4, 0);  QK_PH(3, 1);  VMCNT0; BARRIER;
      KSTAGE(Kb, 5, 1);  QK_PH(4, 0);  VMCNT0; BARRIER;
      VSTAGE(0, 0);      QK_PH(5, 1);
      #pragma unroll
      for (int r = 0; r < 4; ++r) {
        s_t[(qg*16 + hi*4 + r)*68 + cg*32 + frow]      = (sacc[0][r] + vv0)*SCALE_S;
        s_t[(qg*16 + hi*4 + r)*68 + cg*32 + 16 + frow] = (sacc[1][r] + vv1)*SCALE_S;
      }
      VMCNT0; LGKM0; BARRIER;     // V0 landed; s_t visible
      // softmax phase (stage V1; leave it in flight through softmax)
      VSTAGE(1, 1);
      {
        int cbase = t0 + sphys*8;
        float v[8]; float mx = -1e30f;
        #pragma unroll
        for (int j = 0; j < 8; ++j) {
          float s = s_t[srow*68 + sphys*8 + j];
          if (cbase + j > qglob) s = -1e30f;
          v[j] = s; mx = fmaxf(mx, s);
        }
        mx = fmaxf(mx, __shfl_xor(mx, 1));
        mx = fmaxf(mx, __shfl_xor(mx, 2));
        mx = fmaxf(mx, __shfl_xor(mx, 4));
        float mn = fmaxf(m_reg, mx);
        float esc = __expf(m_reg - mn);
        float ps = 0.f; u16 pk[8];
        #pragma unroll
        for (int j = 0; j < 8; ++j) { float p = __expf(v[j] - mn); ps += p; pk[j] = f2bf(p); }
        ps += __shfl_xor(ps, 1); ps += __shfl_xor(ps, 2); ps += __shfl_xor(ps, 4);
        l_reg = l_reg*esc + ps; m_reg = mn;
        if (sphys == 0) e_s[srow] = esc;
        uint4 pv;
        pv.x = (uint32_t)pk[0] | ((uint32_t)pk[1] << 16);
        pv.y = (uint32_t)pk[2] | ((uint32_t)pk[3] << 16);
        pv.z = (uint32_t)pk[4] | ((uint32_t)pk[5] << 16);
        pv.w = (uint32_t)pk[6] | ((uint32_t)pk[7] << 16);
        *(uint4*)(p_t + srow*64 + ((sphys ^ (srow & 7)) << 3)) = pv;
      }
      LGKM0; BARRIER;             // p_t/e_s visible
      // PV0 phase: rescale + P frags, compute V0
      float er[4];
      #pragma unroll
      for (int r = 0; r < 4; ++r) er[r] = e_s[qg*16 + hi*4 + r];
      #pragma unroll
      for (int i = 0; i < 6; ++i)
        #pragma unroll
        for (int j = 0; j < 4; ++j)
          #pragma unroll
          for (int r = 0; r < 4; ++r) acc[i][j][r] *= er[r];
      bf16x8 pa[2];
      #pragma unroll
      for (int kk = 0; kk < 2; ++kk)
        pa[kk] = *(const bf16x8*)(p_t + (qg*16 + frow)*64 + (((kk*4 + hi) ^ fsw) << 3));
      PV_PH(0, 0);       VMCNT0; BARRIER;     // V1 landed
      VSTAGE(2, 0);      PV_PH(1, 1);  VMCNT0; BARRIER;
      VSTAGE(3, 1);      PV_PH(2, 0);  VMCNT0; BARRIER;
      VSTAGE(4, 0);      PV_PH(3, 1);  VMCNT0; BARRIER;
      VSTAGE(5, 1);      PV_PH(4, 0);  VMCNT0; BARRIER;
      if (sn) KSTAGE(Kbn, 0, 0);
      PV_PH(5, 1);       VMCNT0; BARRIER;
      // next tile: K ch0 ready in kls0
    } // tt

    // ---- epilogue ----
    if (sphys == 0) e_s[srow] = l_reg;
    LGKM0; BARRIER;
    float linv[4];
    #pragma unroll
    for (int r = 0; r < 4; ++r) linv[r] = 1.0f / e_s[qg*16 + hi*4 + r];
    #pragma unroll
    for (int i = 0; i < 6; ++i)
      #pragma unroll
      for (int j = 0; j < 4; ++j) {
        int col = i*128 + cg*64 + j*16 + (l & 15);
        #pragma unroll
        for (int r = 0; r < 4; ++r) {
          int row = q0 + qg*16 + hi*4 + r;
          H[(size_t)row*ldh + col] = f2bf(acc[i][j][r]*linv[r]);
        }
      }
    BARRIER;
  } // half
#undef KSTAGE
#undef VSTAGE
#undef QSTAGE
#undef RD_Q
#undef QK_PH
#undef PV_PH
}

// ---------------- host ----------------
extern "C" void kernel_launch(void* const* d_in, const int* in_sizes, int n_in,
                              void* d_out, int out_size, void* d_ws, size_t ws_size,
                              hipStream_t stream) {
  const float* x  = (const float*)d_in[0];
  const float* Wq = (const float*)d_in[1];
  const float* bq = (const float*)d_in[2];
  const float* Wk = (const float*)d_in[3];
  const float* bv = (const float*)d_in[6];
  const float* Wv = (const float*)d_in[5];
  const float* Wc = (const float*)d_in[7];
  const float* bc = (const float*)d_in[8];
  float* out = (float*)d_out;
  // bk enters only through a row-constant softmax term -> cancels

  const size_t XB  = (size_t)MROWS*EMB*sizeof(u16);
  const size_t WHB = (size_t)EMB*EMB*sizeof(u16);
  const size_t VHB = (size_t)MROWS*sizeof(float);
  const size_t AB  = (size_t)EMB*sizeof(float);
  const size_t fixed = XB + 36*WHB + 12*(VHB + AB) + 8192;
  int G = 4;
  while (G > 2 && fixed + (size_t)G*3*XB > ws_size) --G;

  char* ws = (char*)d_ws;
  u16* xb  = (u16*)ws;  ws += XB;
  u16* wvb = (u16*)ws;  ws += 12*WHB;
  u16* wcb = (u16*)ws;  ws += 12*WHB;
  u16* mtb = (u16*)ws;  ws += 12*WHB;
  float* vh = (float*)ws; ws += 12*VHB;
  float* ab = (float*)ws; ws += 12*AB;
  u16* yb  = (u16*)ws;  ws += (size_t)G*XB;
  u16* vtb = (u16*)ws;  ws += (size_t)G*XB;
  u16* hbf = (u16*)ws;  ws += (size_t)G*XB;
  // one-time transposed-weight scratch aliases hbf (wqT) and vtb (wkT)
  u16* wqT = hbf;
  u16* wkT = vtb;

  // ---- one-time prep (all 12 heads) ----
  k_cvt<<<dim3(3072), dim3(256), 0, stream>>>(x, xb, (long)MROWS*EMB);
  k_cvtT<<<dim3(12, 12, 24), dim3(256), 0, stream>>>(Wq, Wk, wqT, wkT, 12);
  k_cvt<<<dim3((unsigned)((12L*EMB*EMB/8)/256)), dim3(256), 0, stream>>>(
      Wv, wvb, 12L*EMB*EMB);
  k_cvtwc<<<dim3((unsigned)((768L*12*EMB/4)/256)), dim3(256), 0, stream>>>(Wc, wcb, 12, 0);
  k_gemm<<<dim3(6, 6, 12), dim3(256), 0, stream>>>(
      wkT, (long)EMB*EMB, EMB, wqT, (long)EMB*EMB, EMB, EMB,
      mtb, (float*)0, (long)EMB*EMB, EMB,
      (const float*)0, (const float*)0, 0L, 9999, 0, 0);
  k_mka<<<dim3(3, 12), dim3(256), 0, stream>>>(wkT, bq, ab);
  k_mkv<<<dim3(1024, 12), dim3(512), 0, stream>>>(xb, ab, vh);

  for (int h0 = 0; h0 < NHEAD; h0 += G) {
    int Gi = (G < NHEAD - h0) ? G : (NHEAD - h0);
    // fused launch: z=0 -> y = x*Mt^T (sliced bf16), z=1 -> Vt = Wv*x^T + bv
    Gemm256Args ay = { xb, EMB, mtb + (size_t)h0*EMB*EMB, EMB, EMB,
                       yb, (long)MROWS*EMB, 768,
                       (const float*)0, (const float*)0, Gi, 0, 0 };
    Gemm256Args av = { wvb + (size_t)h0*EMB*EMB, EMB, xb, EMB, EMB,
                       vtb, 0L, MROWS,
                       bv + (size_t)h0*EMB, (const float*)0, 9999, 1, 1 };
    k_gemm256d<<<dim3(32, 3*Gi, 2), dim3(512), 0, stream>>>(ay, av);
    // flash attention (K = xb) -> hbf [8192, Gi*768]; 512 blocks, 2/CU
    k_attn<<<dim3(16*NBAT*Gi), dim3(256), 0, stream>>>(
        yb, xb, vtb, vh + (size_t)h0*MROWS, hbf, Gi*EMB);
    // out += heads_group * Wc_group^T (+bc on first group)
    k_gemm<<<dim3(64, 6, 1), dim3(256), 0, stream>>>(
        hbf, 0L, Gi*EMB, wcb + (size_t)h0*EMB, 0L, NHEAD*EMB, Gi*EMB,
        (u16*)0, out, 0L, EMB,
        (h0 == 0 ? bc : (const float*)0), (const float*)0, 0L, 9999,
        (h0 == 0 ? 2 : 3), 0);
  }
}

// Round 12
// 1069.116 us; speedup vs baseline: 1.0651x; 1.0651x over previous
//
#include <hip/hip_runtime.h>
#include <hip/hip_bf16.h>
#include <stdint.h>

#define SEQ    1024
#define NBAT   8
#define EMB    768
#define NHEAD  12
#define MROWS  (NBAT*SEQ)            // 8192
#define SCALE_S 0.03608439182435161f // 1/sqrt(768)

typedef unsigned short u16;
typedef __attribute__((ext_vector_type(8))) short bf16x8;
typedef __attribute__((ext_vector_type(4))) float f32x4;

typedef void __attribute__((address_space(1)))* gas_ptr;
typedef void __attribute__((address_space(3)))* las_ptr;

__device__ __forceinline__ void gload16(const void* g, void* l) {
  __builtin_amdgcn_global_load_lds((gas_ptr)(void*)g, (las_ptr)l, 16, 0, 0);
}

#define VMCNT0 asm volatile("s_waitcnt vmcnt(0)" ::: "memory")
#define VMCNT2 asm volatile("s_waitcnt vmcnt(2)" ::: "memory")
#define VMCNT4 asm volatile("s_waitcnt vmcnt(4)" ::: "memory")
#define VMCNT6 asm volatile("s_waitcnt vmcnt(6)" ::: "memory")
#define LGKM0  asm volatile("s_waitcnt lgkmcnt(0)" ::: "memory")
#define BARRIER asm volatile("s_barrier" ::: "memory")

__device__ __forceinline__ u16 f2bf(float f) {
  union { float f; uint32_t u; } a; a.f = f;
  uint32_t r = a.u + 0x7fffu + ((a.u >> 16) & 1u);
  return (u16)(r >> 16);
}
__device__ __forceinline__ float bf2f(u16 b) {
  union { uint32_t u; float f; } c; c.u = (uint32_t)b << 16; return c.f;
}
__device__ __forceinline__ uint32_t pack2(float a, float b) {
  return (uint32_t)f2bf(a) | ((uint32_t)f2bf(b) << 16);
}

// ---------------- conversion / prep kernels ----------------
__global__ void k_cvt(const float* __restrict__ s, u16* __restrict__ d, long n) {
  long i = ((long)blockIdx.x*blockDim.x + threadIdx.x)*8;
  if (i >= n) return;
  float4 a = *(const float4*)(s+i);
  float4 b = *(const float4*)(s+i+4);
  uint4 o; o.x = pack2(a.x,a.y); o.y = pack2(a.z,a.w);
  o.z = pack2(b.x,b.y); o.w = pack2(b.z,b.w);
  *(uint4*)(d+i) = o;
}

// transpose-convert: f32 [768][768] (row=d) -> bf16 [768][768] (row=e)
__global__ void k_cvtT(const float* __restrict__ wq, const float* __restrict__ wk,
                       u16* __restrict__ dq, u16* __restrict__ dk, int Gi) {
  __shared__ float t[64][65];
  int z = blockIdx.z;
  const float* src = (z < Gi) ? wq + (size_t)z*EMB*EMB : wk + (size_t)(z-Gi)*EMB*EMB;
  u16* dst = (z < Gi) ? dq + (size_t)z*EMB*EMB : dk + (size_t)(z-Gi)*EMB*EMB;
  int d0 = blockIdx.x*64, e0 = blockIdx.y*64;
  int tt = threadIdx.x;
  int el = tt & 63, db = tt >> 6;
  #pragma unroll
  for (int p = 0; p < 16; ++p) {
    int dl = p*4 + db;
    t[dl][el] = src[(size_t)(d0+dl)*EMB + e0 + el];
  }
  __syncthreads();
  int dl2 = tt & 63, eb = tt >> 6;
  #pragma unroll
  for (int p = 0; p < 16; ++p) {
    int e2 = p*4 + eb;
    dst[(size_t)(e0+e2)*EMB + d0 + dl2] = f2bf(t[dl2][e2]);
  }
}

// convert full Wc [768, 9216] -> bf16
__global__ void k_cvtwc(const float* __restrict__ wc, u16* __restrict__ d, int Gi, int h0) {
  long ncol = (long)Gi*EMB;
  long i = ((long)blockIdx.x*blockDim.x + threadIdx.x)*4;
  if (i >= 768*ncol) return;
  long eo = i / ncol, c = i - eo*ncol;
  long g = c / EMB, dd = c - g*EMB;
  const float* s = wc + eo*(long)(NHEAD*EMB) + (h0+g)*EMB + dd;
  float4 a = *(const float4*)s;
  uint2 o; o.x = pack2(a.x,a.y); o.y = pack2(a.z,a.w);
  *(uint2*)(d+i) = o;
}

// a[g][e] = sum_d Wk[d][e]*bq[d]   (wkT row-major [e][d])
__global__ void k_mka(const u16* __restrict__ wkT, const float* __restrict__ bq,
                      float* __restrict__ a) {
  int g = blockIdx.y;
  int e = blockIdx.x*256 + threadIdx.x;
  const u16* row = wkT + (size_t)g*EMB*EMB + (size_t)e*EMB;
  const float* b = bq + (size_t)g*EMB;
  float s = 0.f;
  for (int d = 0; d < EMB; ++d) s += bf2f(row[d]) * b[d];
  a[(size_t)g*EMB + e] = s;
}

// v[g][i] = sum_e xb[i][e]*a[g][e]   (wave per row)
__global__ void k_mkv(const u16* __restrict__ xb, const float* __restrict__ a,
                      float* __restrict__ v) {
  int g = blockIdx.y;
  int w = threadIdx.x >> 6, l = threadIdx.x & 63;
  int i = blockIdx.x*8 + w;
  const u16* xr = xb + (size_t)i*EMB;
  const float* ag = a + (size_t)g*EMB;
  float s = 0.f;
  #pragma unroll
  for (int c = 0; c < 12; ++c) {
    int e = c*64 + l;
    s += bf2f(xr[e]) * ag[e];
  }
  s += __shfl_xor(s, 1); s += __shfl_xor(s, 2); s += __shfl_xor(s, 4);
  s += __shfl_xor(s, 8); s += __shfl_xor(s, 16); s += __shfl_xor(s, 32);
  if (l == 0) v[(size_t)g*MROWS + i] = s;
}

// ---------------- dual 256x256 NT GEMM (r4 structure; two configs per launch) ----------------
struct Gemm256Args {
  const u16* A; int lda;
  const u16* B; int ldb; int K;
  u16* Cb; long c_hs; int ldc;
  const float* bias; const float* bias2;
  int gsplit; int mode; int swap;
};

__global__ __launch_bounds__(512, 2) void k_gemm256d(Gemm256Args p0, Gemm256Args p1)
{
  __shared__ u16 lsA[2*16384];
  __shared__ u16 lsB[2*16384];

  const Gemm256Args P = blockIdx.z ? p1 : p0;
  int m0 = (P.swap ? blockIdx.y : blockIdx.x) * 256;
  int n0 = (P.swap ? blockIdx.x : blockIdx.y) * 256;
  int tid = threadIdx.x;
  int w = tid >> 6, l = tid & 63;
  int wr = w >> 2, wc = w & 3;

  const u16* gA = P.A + (size_t)(m0 + 32*w + (l>>3))*P.lda + (((l&7) ^ (l>>3)) << 3);
  const u16* gB = P.B + (size_t)(n0 + 32*w + (l>>3))*P.ldb + (((l&7) ^ (l>>3)) << 3);

#define STAGE256(t, buf) do { \
    int k0_ = (t)*64; \
    _Pragma("unroll") \
    for (int c_ = 0; c_ < 4; ++c_) \
      gload16(gA + (size_t)(c_*8)*P.lda + k0_, lsA + (buf)*16384 + (32*w + 8*c_)*64); \
    _Pragma("unroll") \
    for (int c_ = 0; c_ < 4; ++c_) \
      gload16(gB + (size_t)(c_*8)*P.ldb + k0_, lsB + (buf)*16384 + (32*w + 8*c_)*64); \
  } while(0)

  f32x4 acc[8][4];
  #pragma unroll
  for (int i = 0; i < 8; ++i)
    #pragma unroll
    for (int j = 0; j < 4; ++j) acc[i][j] = (f32x4)0.0f;

  int nt = P.K >> 6;
  STAGE256(0, 0);
  for (int t = 0; t < nt; ++t) {
    VMCNT0; BARRIER;
    if (t + 1 < nt) STAGE256(t+1, (t+1)&1);
    const u16* la = lsA + (t&1)*16384;
    const u16* lb = lsB + (t&1)*16384;
    #pragma unroll
    for (int ks = 0; ks < 2; ++ks) {
      int off = (((4*ks + (l>>4)) ^ (l&7)) << 3);
      bf16x8 af[8], bf_[4];
      #pragma unroll
      for (int fi = 0; fi < 8; ++fi)
        af[fi] = *(const bf16x8*)(la + (wr*128 + fi*16 + (l&15))*64 + off);
      #pragma unroll
      for (int fj = 0; fj < 4; ++fj)
        bf_[fj] = *(const bf16x8*)(lb + (wc*64 + fj*16 + (l&15))*64 + off);
      __builtin_amdgcn_s_setprio(1);
      #pragma unroll
      for (int fi = 0; fi < 8; ++fi)
        #pragma unroll
        for (int fj = 0; fj < 4; ++fj)
          acc[fi][fj] = __builtin_amdgcn_mfma_f32_16x16x32_bf16(af[fi], bf_[fj], acc[fi][fj], 0, 0, 0);
      __builtin_amdgcn_s_setprio(0);
    }
  }
#undef STAGE256

  if (P.mode == 0) {
    int s = n0 / 768;
    int dbase = n0 - s*768 + wc*64;
    const float* bsl = P.bias ? ((s < P.gsplit) ? P.bias + (size_t)s*768
                                                : P.bias2 + (size_t)(s - P.gsplit)*768)
                              : (const float*)0;
    u16* Cs = P.Cb + (size_t)s*P.c_hs;
    #pragma unroll
    for (int fj = 0; fj < 4; ++fj) {
      int dcol = dbase + fj*16 + (l&15);
      float bb = bsl ? bsl[dcol] : 0.f;
      #pragma unroll
      for (int fi = 0; fi < 8; ++fi) {
        #pragma unroll
        for (int r = 0; r < 4; ++r) {
          int row = m0 + wr*128 + fi*16 + (l>>4)*4 + r;
          Cs[(size_t)row*768 + dcol] = f2bf(acc[fi][fj][r] + bb);
        }
      }
    }
  } else {
    #pragma unroll
    for (int fi = 0; fi < 8; ++fi) {
      #pragma unroll
      for (int r = 0; r < 4; ++r) {
        int row = m0 + wr*128 + fi*16 + (l>>4)*4 + r;
        float bb = P.bias[row];
        #pragma unroll
        for (int fj = 0; fj < 4; ++fj) {
          int cbn = n0 + wc*64 + fj*16 + (l&15);
          P.Cb[(size_t)row*P.ldc + cbn] = f2bf(acc[fi][fj][r] + bb);
        }
      }
    }
  }
}

// ---------------- NT GEMM: 128x128 tile (Mt + output projection) ----------------
__global__ __launch_bounds__(256) void k_gemm(
    const u16* __restrict__ A, long a_hs, int lda,
    const u16* __restrict__ B, long b_hs, int ldb, int K,
    u16* Cb, float* Cf, long c_hs, int ldc,
    const float* __restrict__ bias, const float* __restrict__ bias2,
    long bias_hs, int gsplit, int mode, int swapxy)
{
  __shared__ u16 lsA[3*4096];
  __shared__ u16 lsB[3*4096];
  int g = blockIdx.z;
  const u16* Ag = A + (long)g*a_hs;
  const u16* Bg = B + (long)g*b_hs;
  int tm = swapxy ? blockIdx.y : blockIdx.x;
  int tn = swapxy ? blockIdx.x : blockIdx.y;
  int m0 = tm*128, n0 = tn*128;
  int tid = threadIdx.x;
  int w = tid >> 6, l = tid & 63;

  int srow = l >> 2;
  int scol = ((l & 3) ^ ((l >> 3) & 3)) * 8;
  const u16* ga0 = Ag + (long)(m0 + (2*w)*16   + srow)*lda + scol;
  const u16* ga1 = Ag + (long)(m0 + (2*w+1)*16 + srow)*lda + scol;
  const u16* gb0 = Bg + (long)(n0 + (2*w)*16   + srow)*ldb + scol;
  const u16* gb1 = Bg + (long)(n0 + (2*w+1)*16 + srow)*ldb + scol;

#define GSTAGE(k0, buf) do { \
    gload16(ga0 + (k0), lsA + (buf)*4096 + (2*w)*512); \
    gload16(ga1 + (k0), lsA + (buf)*4096 + (2*w+1)*512); \
    gload16(gb0 + (k0), lsB + (buf)*4096 + (2*w)*512); \
    gload16(gb1 + (k0), lsB + (buf)*4096 + (2*w+1)*512); \
  } while(0)

  f32x4 acc[4][4];
  #pragma unroll
  for (int i = 0; i < 4; ++i)
    #pragma unroll
    for (int j = 0; j < 4; ++j) acc[i][j] = (f32x4)0.0f;

  int wr = w >> 1, wc_ = w & 1;
  int frow = l & 15;
  int sp = (l >> 4) ^ ((frow >> 1) & 3);
  int aoff[4], boff[4];
  #pragma unroll
  for (int i = 0; i < 4; ++i) {
    aoff[i] = (wr*64 + i*16 + frow)*32 + sp*8;
    boff[i] = (wc_*64 + i*16 + frow)*32 + sp*8;
  }

  int nt = K >> 5;
  GSTAGE(0, 0);
  GSTAGE(32, 1);
  VMCNT4; BARRIER;
  int cur = 0;
  for (int t = 0; t < nt; ++t) {
    if (t + 2 < nt) {
      int nb = cur + 2; if (nb >= 3) nb -= 3;
      GSTAGE((t+2) << 5, nb);
    }
    const u16* la = lsA + cur*4096;
    const u16* lb = lsB + cur*4096;
    bf16x8 af[4], bfr[4];
    #pragma unroll
    for (int i = 0; i < 4; ++i) af[i] = *(const bf16x8*)(la + aoff[i]);
    #pragma unroll
    for (int j = 0; j < 4; ++j) bfr[j] = *(const bf16x8*)(lb + boff[j]);
    #pragma unroll
    for (int i = 0; i < 4; ++i)
      #pragma unroll
      for (int j = 0; j < 4; ++j)
        acc[i][j] = __builtin_amdgcn_mfma_f32_16x16x32_bf16(af[i], bfr[j], acc[i][j], 0, 0, 0);
    if (t + 2 < nt) { VMCNT4; } else { VMCNT0; }
    LGKM0; BARRIER;
    cur = (cur == 2) ? 0 : cur + 1;
  }
#undef GSTAGE

  u16* Cbg = Cb ? Cb + (long)g*c_hs : (u16*)0;
  const float* bsel = (g < gsplit) ? bias : bias2;
  long gi = (g < gsplit) ? g : g - gsplit;
  const float* bs = bsel ? bsel + gi*bias_hs : (const float*)0;
  int rl = (l >> 4)*4, cl = l & 15;
  #pragma unroll
  for (int i = 0; i < 4; ++i) {
    #pragma unroll
    for (int j = 0; j < 4; ++j) {
      int rb = m0 + wr*64 + i*16 + rl;
      int cb = n0 + wc_*64 + j*16 + cl;
      float cbv = 0.f;
      if ((mode == 0 || mode == 2) && bs) cbv = bs[cb];
      #pragma unroll
      for (int r = 0; r < 4; ++r) {
        int rr = rb + r;
        float v = acc[i][j][r];
        v += (mode == 1) ? bs[rr] : cbv;
        size_t idx = (size_t)rr*(size_t)ldc + cb;
        if (mode <= 1) Cbg[idx] = f2bf(v);
        else if (mode == 2) Cf[idx] = v;
        else Cf[idx] += v;
      }
    }
  }
}

// ---------------- flash attention (causal), QBLK=64, KBLK=64, 8 waves ----------------
// r8 structure with 4-buffer kls/vls: every staged chunk gets 2 compute phases
// to land (counted vmcnt(4)/vmcnt(6), never drains in steady state).
// K-operand = xb shared across heads; per-key bias vh.
__global__ __launch_bounds__(512, 2) void k_attn(
    const u16* __restrict__ qb, const u16* __restrict__ xkb,
    const u16* __restrict__ vtb, const float* __restrict__ vh,
    u16* __restrict__ hb, int ldh)
{
  __shared__ u16 kls[4*8192];     // 4 bufs x 16KB (K chunks [64 k][128 e])
  __shared__ u16 vls[4*8192];     // 4 bufs x 16KB (V chunks [128 e][64 t])
  __shared__ float s_t[64*68];
  __shared__ u16 p_t[64*64];
  __shared__ float e_s[64];

  int b = blockIdx.x;
  int xcd = b & 7, kk_ = b >> 3;
  int gn = xcd + 8*(kk_ >> 3), pair = kk_ & 7;
  int g = gn >> 3, n = gn & 7;

  const u16* Q  = qb  + (size_t)g*MROWS*EMB + (size_t)n*SEQ*EMB;
  const u16* Kp = xkb + (size_t)n*SEQ*EMB;
  const u16* Vt = vtb + (size_t)g*EMB*MROWS + (size_t)n*SEQ;
  const float* Vh = vh + (size_t)g*MROWS + (size_t)n*SEQ;
  u16* H = hb + (size_t)(n*SEQ)*ldh + (size_t)g*EMB;

  int tid = threadIdx.x;
  int w = tid >> 6, l = tid & 63;
  int qg = w >> 1;
  int cg = w & 1;
  int frow = l & 15;
  int fsw = frow & 7;
  int srow = tid >> 3;
  int sphys = tid & 7;
  int scol = ((sphys ^ (srow & 7)) << 3);

  // chunk index -> buffer = idx & 3 (reuse distance >= 3 phases everywhere)
#define KSTG(base, pc) do { \
    const u16* s_ = (base) + (pc)*128; \
    u16* d_ = kls + ((pc)&3)*8192 + w*512; \
    gload16(s_,      d_); \
    gload16(s_ + 64, d_ + 4096); \
  } while(0)
#define VSTG(vc) do { \
    const u16* s_ = Vs + (size_t)((vc)*128)*MROWS; \
    u16* d_ = vls + ((vc)&3)*8192 + w*512; \
    gload16(s_,                    d_); \
    gload16(s_ + (size_t)64*MROWS, d_ + 4096); \
  } while(0)
#define QSTG(pc, arr) do { \
    const u16* s_ = Qs + (pc)*128; \
    gload16(s_,      (arr) + w*512); \
    gload16(s_ + 64, (arr) + 4096 + w*512); \
  } while(0)
#define RD_Q(pc, arr) do { \
    _Pragma("unroll") for (int kk2 = 0; kk2 < 2; ++kk2) \
      _Pragma("unroll") for (int kkl = 0; kkl < 2; ++kkl) \
        qreg[2*(pc) + kk2][kkl] = *(const bf16x8*)((arr) + kk2*4096 + (qg*16 + frow)*64 \
                                                   + (((kkl*4 + (l>>4)) ^ fsw) << 3)); \
  } while(0)
#define QK_PH(c) do { \
    const u16* kb_ = kls + ((c)&3)*8192; \
    __builtin_amdgcn_s_setprio(1); \
    _Pragma("unroll") for (int kk2 = 0; kk2 < 2; ++kk2) { \
      _Pragma("unroll") for (int kkl = 0; kkl < 2; ++kkl) { \
        int so = ((kkl*4 + (l>>4)) ^ fsw) << 3; \
        bf16x8 aq = qreg[2*(c) + kk2][kkl]; \
        _Pragma("unroll") for (int cc = 0; cc < 2; ++cc) { \
          bf16x8 bk_ = *(const bf16x8*)(kb_ + kk2*4096 + ((cg*2 + cc)*16 + frow)*64 + so); \
          sacc[cc] = __builtin_amdgcn_mfma_f32_16x16x32_bf16(aq, bk_, sacc[cc], 0, 0, 0); \
        } \
      } \
    } \
    __builtin_amdgcn_s_setprio(0); \
  } while(0)
#define PV_PH(c) do { \
    const u16* vb_ = vls + ((c)&3)*8192; \
    __builtin_amdgcn_s_setprio(1); \
    _Pragma("unroll") for (int cf = 0; cf < 4; ++cf) { \
      _Pragma("unroll") for (int kk = 0; kk < 2; ++kk) { \
        bf16x8 vbf = *(const bf16x8*)(vb_ + (cg*64 + cf*16 + frow)*64 + (((kk*4 + (l>>4)) ^ fsw) << 3)); \
        acc[(c)][cf] = __builtin_amdgcn_mfma_f32_16x16x32_bf16(pa[kk], vbf, acc[(c)][cf], 0, 0, 0); \
      } \
    } \
    __builtin_amdgcn_s_setprio(0); \
  } while(0)

  for (int half = 0; half < 2; ++half) {
    int qt = half ? 15 - pair : pair;
    int q0 = qt * 64;
    int nt = qt + 1;

    f32x4 acc[6][4];
    #pragma unroll
    for (int i = 0; i < 6; ++i)
      #pragma unroll
      for (int j = 0; j < 4; ++j) acc[i][j] = (f32x4)0.0f;
    float m_reg = -1e30f, l_reg = 0.f;

    // ---- prologue: Q chunks 0..5 -> qreg; K0..K2 staged behind ----
    const u16* Qs  = Q + (size_t)(q0 + srow)*EMB + scol;
    const u16* Ks0 = Kp + (size_t)srow*EMB + scol;
    bf16x8 qreg[12][2];
    VMCNT0;
    QSTG(0, kls); QSTG(1, kls + 8192); QSTG(2, kls + 16384); QSTG(3, kls + 24576);
    VMCNT6; BARRIER;
    QSTG(4, vls);       RD_Q(0, kls);         VMCNT6; LGKM0; BARRIER;
    QSTG(5, vls + 8192); RD_Q(1, kls + 8192); VMCNT6; LGKM0; BARRIER;
    KSTG(Ks0, 0);       RD_Q(2, kls + 16384); VMCNT6; LGKM0; BARRIER;
    KSTG(Ks0, 1);       RD_Q(3, kls + 24576); VMCNT6; LGKM0; BARRIER;
    KSTG(Ks0, 2);       RD_Q(4, vls);         VMCNT6; LGKM0; BARRIER;
                        RD_Q(5, vls + 8192);  LGKM0;
    // K0,K1,K2 in flight / landed; tile top enforces K0

    for (int tt = 0; tt < nt; ++tt) {
      int t0 = tt*64;
      const u16* Ks  = Kp + (size_t)(t0 + srow)*EMB + scol;
      const u16* Ksn = Kp + (size_t)(t0 + 64 + srow)*EMB + scol;
      const u16* Vs  = Vt + (size_t)srow*MROWS + t0 + scol;
      bool sn = (tt + 1 < nt);
      float vv0 = Vh[t0 + cg*32 + frow];
      float vv1 = Vh[t0 + cg*32 + 16 + frow];
      VMCNT4; BARRIER;                     // K0 landed (K1,K2-ish in flight)

      f32x4 sacc[2]; sacc[0] = (f32x4)0.0f; sacc[1] = (f32x4)0.0f;
      KSTG(Ks, 3); QK_PH(0); VMCNT4; LGKM0; BARRIER;
      KSTG(Ks, 4); QK_PH(1); VMCNT4; LGKM0; BARRIER;
      KSTG(Ks, 5); QK_PH(2); VMCNT4; LGKM0; BARRIER;
      VSTG(0);     QK_PH(3); VMCNT4; LGKM0; BARRIER;
      VSTG(1);     QK_PH(4); VMCNT4; LGKM0; BARRIER;
      VSTG(2);     QK_PH(5);
      #pragma unroll
      for (int r = 0; r < 4; ++r) {
        s_t[(qg*16 + (l>>4)*4 + r)*68 + cg*32 + frow]      = (sacc[0][r] + vv0)*SCALE_S;
        s_t[(qg*16 + (l>>4)*4 + r)*68 + cg*32 + 16 + frow] = (sacc[1][r] + vv1)*SCALE_S;
      }
      LGKM0; BARRIER;                      // s_t visible; V0..V2 in flight (6)
      // ---- softmax phase (stages V3) ----
      VSTG(3);
      {
        int qglob = q0 + srow;
        int cbase = t0 + sphys*8;
        float v[8]; float mx = -1e30f;
        #pragma unroll
        for (int j = 0; j < 8; ++j) {
          float s = s_t[srow*68 + sphys*8 + j];
          if (cbase + j > qglob) s = -1e30f;
          v[j] = s; mx = fmaxf(mx, s);
        }
        mx = fmaxf(mx, __shfl_xor(mx, 1));
        mx = fmaxf(mx, __shfl_xor(mx, 2));
        mx = fmaxf(mx, __shfl_xor(mx, 4));
        float mn = fmaxf(m_reg, mx);
        float esc = __expf(m_reg - mn);
        float ps = 0.f; u16 pk[8];
        #pragma unroll
        for (int j = 0; j < 8; ++j) { float p = __expf(v[j] - mn); ps += p; pk[j] = f2bf(p); }
        ps += __shfl_xor(ps, 1); ps += __shfl_xor(ps, 2); ps += __shfl_xor(ps, 4);
        l_reg = l_reg*esc + ps; m_reg = mn;
        if (sphys == 0) e_s[srow] = esc;
        uint4 pv;
        pv.x = (uint32_t)pk[0] | ((uint32_t)pk[1] << 16);
        pv.y = (uint32_t)pk[2] | ((uint32_t)pk[3] << 16);
        pv.z = (uint32_t)pk[4] | ((uint32_t)pk[5] << 16);
        pv.w = (uint32_t)pk[6] | ((uint32_t)pk[7] << 16);
        *(uint4*)(p_t + srow*64 + ((sphys ^ (srow & 7)) << 3)) = pv;
      }
      VMCNT6; LGKM0; BARRIER;              // V0 landed; p_t/e_s visible
      // ---- rescale + P frags; PV ----
      float er[4];
      #pragma unroll
      for (int r = 0; r < 4; ++r) er[r] = e_s[qg*16 + (l>>4)*4 + r];
      #pragma unroll
      for (int i = 0; i < 6; ++i)
        #pragma unroll
        for (int j = 0; j < 4; ++j)
          #pragma unroll
          for (int r = 0; r < 4; ++r) acc[i][j][r] *= er[r];
      bf16x8 pa[2];
      #pragma unroll
      for (int kk = 0; kk < 2; ++kk)
        pa[kk] = *(const bf16x8*)(p_t + (qg*16 + frow)*64 + (((kk*4 + (l>>4)) ^ fsw) << 3));
                   PV_PH(0); VMCNT4; LGKM0; BARRIER;   // V1 landed
      VSTG(4);     PV_PH(1); VMCNT4; LGKM0; BARRIER;   // V2 landed
      VSTG(5);     PV_PH(2); VMCNT4; LGKM0; BARRIER;   // V3 landed
      if (sn) KSTG(Ksn, 0);
                   PV_PH(3);
      if (sn) { VMCNT4; } else { VMCNT2; }
      LGKM0; BARRIER;                                   // V4 landed
      if (sn) KSTG(Ksn, 1);
                   PV_PH(4);
      if (sn) { VMCNT4; } else { VMCNT0; }
      LGKM0; BARRIER;                                   // V5 landed
      if (sn) KSTG(Ksn, 2);
                   PV_PH(5);
      if (!sn) { VMCNT0; LGKM0; BARRIER; }
      // sn: next tile top VMCNT4;BARRIER covers K'0
    } // tt

    // ---- epilogue ----
    if (sphys == 0) e_s[srow] = l_reg;
    LGKM0; BARRIER;
    float linv[4];
    #pragma unroll
    for (int r = 0; r < 4; ++r) linv[r] = 1.0f / e_s[qg*16 + (l>>4)*4 + r];
    #pragma unroll
    for (int i = 0; i < 6; ++i)
      #pragma unroll
      for (int j = 0; j < 4; ++j) {
        int col = i*128 + cg*64 + j*16 + (l & 15);
        #pragma unroll
        for (int r = 0; r < 4; ++r) {
          int row = q0 + qg*16 + (l>>4)*4 + r;
          H[(size_t)row*ldh + col] = f2bf(acc[i][j][r]*linv[r]);
        }
      }
    BARRIER;
  } // half
#undef KSTG
#undef VSTG
#undef QSTG
#undef RD_Q
#undef QK_PH
#undef PV_PH
}

// ---------------- host ----------------
extern "C" void kernel_launch(void* const* d_in, const int* in_sizes, int n_in,
                              void* d_out, int out_size, void* d_ws, size_t ws_size,
                              hipStream_t stream) {
  const float* x  = (const float*)d_in[0];
  const float* Wq = (const float*)d_in[1];
  const float* bq = (const float*)d_in[2];
  const float* Wk = (const float*)d_in[3];
  const float* bv = (const float*)d_in[6];
  const float* Wv = (const float*)d_in[5];
  const float* Wc = (const float*)d_in[7];
  const float* bc = (const float*)d_in[8];
  float* out = (float*)d_out;
  // bk enters only through a row-constant softmax term -> cancels

  const size_t XB  = (size_t)MROWS*EMB*sizeof(u16);
  const size_t WHB = (size_t)EMB*EMB*sizeof(u16);
  const size_t VHB = (size_t)MROWS*sizeof(float);
  const size_t AB  = (size_t)EMB*sizeof(float);
  const size_t fixed = XB + 36*WHB + 12*(VHB + AB) + 8192;
  int G = 4;
  while (G > 2 && fixed + (size_t)G*3*XB > ws_size) --G;

  char* ws = (char*)d_ws;
  u16* xb  = (u16*)ws;  ws += XB;
  u16* wvb = (u16*)ws;  ws += 12*WHB;
  u16* wcb = (u16*)ws;  ws += 12*WHB;
  u16* mtb = (u16*)ws;  ws += 12*WHB;
  float* vh = (float*)ws; ws += 12*VHB;
  float* ab = (float*)ws; ws += 12*AB;
  u16* yb  = (u16*)ws;  ws += (size_t)G*XB;
  u16* vtb = (u16*)ws;  ws += (size_t)G*XB;
  u16* hbf = (u16*)ws;  ws += (size_t)G*XB;
  // one-time transposed-weight scratch aliases hbf (wqT) and vtb (wkT)
  u16* wqT = hbf;
  u16* wkT = vtb;

  // ---- one-time prep (all 12 heads) ----
  k_cvt<<<dim3(3072), dim3(256), 0, stream>>>(x, xb, (long)MROWS*EMB);
  k_cvtT<<<dim3(12, 12, 24), dim3(256), 0, stream>>>(Wq, Wk, wqT, wkT, 12);
  k_cvt<<<dim3((unsigned)((12L*EMB*EMB/8)/256)), dim3(256), 0, stream>>>(
      Wv, wvb, 12L*EMB*EMB);
  k_cvtwc<<<dim3((unsigned)((768L*12*EMB/4)/256)), dim3(256), 0, stream>>>(Wc, wcb, 12, 0);
  k_gemm<<<dim3(6, 6, 12), dim3(256), 0, stream>>>(
      wkT, (long)EMB*EMB, EMB, wqT, (long)EMB*EMB, EMB, EMB,
      mtb, (float*)0, (long)EMB*EMB, EMB,
      (const float*)0, (const float*)0, 0L, 9999, 0, 0);
  k_mka<<<dim3(3, 12), dim3(256), 0, stream>>>(wkT, bq, ab);
  k_mkv<<<dim3(1024, 12), dim3(512), 0, stream>>>(xb, ab, vh);

  for (int h0 = 0; h0 < NHEAD; h0 += G) {
    int Gi = (G < NHEAD - h0) ? G : (NHEAD - h0);
    // fused launch: z=0 -> y = x*Mt^T (sliced bf16), z=1 -> Vt = Wv*x^T + bv
    Gemm256Args ay = { xb, EMB, mtb + (size_t)h0*EMB*EMB, EMB, EMB,
                       yb, (long)MROWS*EMB, 768,
                       (const float*)0, (const float*)0, Gi, 0, 0 };
    Gemm256Args av = { wvb + (size_t)h0*EMB*EMB, EMB, xb, EMB, EMB,
                       vtb, 0L, MROWS,
                       bv + (size_t)h0*EMB, (const float*)0, 9999, 1, 1 };
    k_gemm256d<<<dim3(32, 3*Gi, 2), dim3(512), 0, stream>>>(ay, av);
    // flash attention (K = xb) -> hbf [8192, Gi*768]
    k_attn<<<dim3(8*NBAT*Gi), dim3(512), 0, stream>>>(
        yb, xb, vtb, vh + (size_t)h0*MROWS, hbf, Gi*EMB);
    // out += heads_group * Wc_group^T (+bc on first group)
    k_gemm<<<dim3(64, 6, 1), dim3(256), 0, stream>>>(
        hbf, 0L, Gi*EMB, wcb + (size_t)h0*EMB, 0L, NHEAD*EMB, Gi*EMB,
        (u16*)0, out, 0L, EMB,
        (h0 == 0 ? bc : (const float*)0), (const float*)0, 0L, 9999,
        (h0 == 0 ? 2 : 3), 0);
  }
}

// Round 13
// 1056.290 us; speedup vs baseline: 1.0780x; 1.0121x over previous
//
#include <hip/hip_runtime.h>
#include <hip/hip_bf16.h>
#include <stdint.h>

#define SEQ    1024
#define NBAT   8
#define EMB    768
#define NHEAD  12
#define MROWS  (NBAT*SEQ)            // 8192
#define SCALE_S 0.03608439182435161f // 1/sqrt(768)

typedef unsigned short u16;
typedef __attribute__((ext_vector_type(8))) short bf16x8;
typedef __attribute__((ext_vector_type(4))) float f32x4;

typedef void __attribute__((address_space(1)))* gas_ptr;
typedef void __attribute__((address_space(3)))* las_ptr;

__device__ __forceinline__ void gload16(const void* g, void* l) {
  __builtin_amdgcn_global_load_lds((gas_ptr)(void*)g, (las_ptr)l, 16, 0, 0);
}

#define VMCNT0 asm volatile("s_waitcnt vmcnt(0)" ::: "memory")
#define VMCNT2 asm volatile("s_waitcnt vmcnt(2)" ::: "memory")
#define VMCNT4 asm volatile("s_waitcnt vmcnt(4)" ::: "memory")
#define LGKM0  asm volatile("s_waitcnt lgkmcnt(0)" ::: "memory")
#define BARRIER asm volatile("s_barrier" ::: "memory")

__device__ __forceinline__ u16 f2bf(float f) {
  union { float f; uint32_t u; } a; a.f = f;
  uint32_t r = a.u + 0x7fffu + ((a.u >> 16) & 1u);
  return (u16)(r >> 16);
}
__device__ __forceinline__ float bf2f(u16 b) {
  union { uint32_t u; float f; } c; c.u = (uint32_t)b << 16; return c.f;
}
__device__ __forceinline__ uint32_t pack2(float a, float b) {
  return (uint32_t)f2bf(a) | ((uint32_t)f2bf(b) << 16);
}

// ---------------- conversion / prep kernels ----------------
__global__ void k_cvt(const float* __restrict__ s, u16* __restrict__ d, long n) {
  long i = ((long)blockIdx.x*blockDim.x + threadIdx.x)*8;
  if (i >= n) return;
  float4 a = *(const float4*)(s+i);
  float4 b = *(const float4*)(s+i+4);
  uint4 o; o.x = pack2(a.x,a.y); o.y = pack2(a.z,a.w);
  o.z = pack2(b.x,b.y); o.w = pack2(b.z,b.w);
  *(uint4*)(d+i) = o;
}

// transpose-convert: f32 [768][768] (row=d) -> bf16 [768][768] (row=e)
__global__ void k_cvtT(const float* __restrict__ wq, const float* __restrict__ wk,
                       u16* __restrict__ dq, u16* __restrict__ dk, int Gi) {
  __shared__ float t[64][65];
  int z = blockIdx.z;
  const float* src = (z < Gi) ? wq + (size_t)z*EMB*EMB : wk + (size_t)(z-Gi)*EMB*EMB;
  u16* dst = (z < Gi) ? dq + (size_t)z*EMB*EMB : dk + (size_t)(z-Gi)*EMB*EMB;
  int d0 = blockIdx.x*64, e0 = blockIdx.y*64;
  int tt = threadIdx.x;
  int el = tt & 63, db = tt >> 6;
  #pragma unroll
  for (int p = 0; p < 16; ++p) {
    int dl = p*4 + db;
    t[dl][el] = src[(size_t)(d0+dl)*EMB + e0 + el];
  }
  __syncthreads();
  int dl2 = tt & 63, eb = tt >> 6;
  #pragma unroll
  for (int p = 0; p < 16; ++p) {
    int e2 = p*4 + eb;
    dst[(size_t)(e0+e2)*EMB + d0 + dl2] = f2bf(t[dl2][e2]);
  }
}

// convert full Wc [768, 9216] -> bf16
__global__ void k_cvtwc(const float* __restrict__ wc, u16* __restrict__ d, int Gi, int h0) {
  long ncol = (long)Gi*EMB;
  long i = ((long)blockIdx.x*blockDim.x + threadIdx.x)*4;
  if (i >= 768*ncol) return;
  long eo = i / ncol, c = i - eo*ncol;
  long g = c / EMB, dd = c - g*EMB;
  const float* s = wc + eo*(long)(NHEAD*EMB) + (h0+g)*EMB + dd;
  float4 a = *(const float4*)s;
  uint2 o; o.x = pack2(a.x,a.y); o.y = pack2(a.z,a.w);
  *(uint2*)(d+i) = o;
}

// a[g][e] = sum_d Wk[d][e]*bq[d]   (wkT row-major [e][d])
__global__ void k_mka(const u16* __restrict__ wkT, const float* __restrict__ bq,
                      float* __restrict__ a) {
  int g = blockIdx.y;
  int e = blockIdx.x*256 + threadIdx.x;
  const u16* row = wkT + (size_t)g*EMB*EMB + (size_t)e*EMB;
  const float* b = bq + (size_t)g*EMB;
  float s = 0.f;
  for (int d = 0; d < EMB; ++d) s += bf2f(row[d]) * b[d];
  a[(size_t)g*EMB + e] = s;
}

// v[g][i] = sum_e xb[i][e]*a[g][e]   (wave per row)
__global__ void k_mkv(const u16* __restrict__ xb, const float* __restrict__ a,
                      float* __restrict__ v) {
  int g = blockIdx.y;
  int w = threadIdx.x >> 6, l = threadIdx.x & 63;
  int i = blockIdx.x*8 + w;
  const u16* xr = xb + (size_t)i*EMB;
  const float* ag = a + (size_t)g*EMB;
  float s = 0.f;
  #pragma unroll
  for (int c = 0; c < 12; ++c) {
    int e = c*64 + l;
    s += bf2f(xr[e]) * ag[e];
  }
  s += __shfl_xor(s, 1); s += __shfl_xor(s, 2); s += __shfl_xor(s, 4);
  s += __shfl_xor(s, 8); s += __shfl_xor(s, 16); s += __shfl_xor(s, 32);
  if (l == 0) v[(size_t)g*MROWS + i] = s;
}

// ---------------- triple 256x256 NT GEMM (r4 structure; up to 3 configs/launch) ----------------
// modes: 0 = bf16 out, sliced cols (768 slices, stride c_hs), optional col-bias split;
//        1 = bf16 out, plain ldc, row-bias;
//        2 = f32 out store + col-bias;  3 = f32 accumulate (no bias).
struct Gemm256Args {
  const u16* A; int lda;
  const u16* B; int ldb; int K;
  u16* Cb; float* Cf; long c_hs; int ldc;
  const float* bias; const float* bias2;
  int gsplit; int mode; int swap; int ny;
};

__global__ __launch_bounds__(512, 2) void k_gemm256t(Gemm256Args p0, Gemm256Args p1,
                                                     Gemm256Args p2)
{
  __shared__ u16 lsA[2*16384];
  __shared__ u16 lsB[2*16384];

  Gemm256Args P; int y = blockIdx.y;
  if (y < p0.ny) { P = p0; }
  else if (y < p0.ny + p1.ny) { P = p1; y -= p0.ny; }
  else { P = p2; y -= p0.ny + p1.ny; }
  int m0 = (P.swap ? y : (int)blockIdx.x) * 256;
  int n0 = (P.swap ? (int)blockIdx.x : y) * 256;
  int tid = threadIdx.x;
  int w = tid >> 6, l = tid & 63;
  int wr = w >> 2, wc = w & 3;

  const u16* gA = P.A + (size_t)(m0 + 32*w + (l>>3))*P.lda + (((l&7) ^ (l>>3)) << 3);
  const u16* gB = P.B + (size_t)(n0 + 32*w + (l>>3))*P.ldb + (((l&7) ^ (l>>3)) << 3);

#define STAGE256(t, buf) do { \
    int k0_ = (t)*64; \
    _Pragma("unroll") \
    for (int c_ = 0; c_ < 4; ++c_) \
      gload16(gA + (size_t)(c_*8)*P.lda + k0_, lsA + (buf)*16384 + (32*w + 8*c_)*64); \
    _Pragma("unroll") \
    for (int c_ = 0; c_ < 4; ++c_) \
      gload16(gB + (size_t)(c_*8)*P.ldb + k0_, lsB + (buf)*16384 + (32*w + 8*c_)*64); \
  } while(0)

  f32x4 acc[8][4];
  #pragma unroll
  for (int i = 0; i < 8; ++i)
    #pragma unroll
    for (int j = 0; j < 4; ++j) acc[i][j] = (f32x4)0.0f;

  int nt = P.K >> 6;
  STAGE256(0, 0);
  for (int t = 0; t < nt; ++t) {
    VMCNT0; BARRIER;
    if (t + 1 < nt) STAGE256(t+1, (t+1)&1);
    const u16* la = lsA + (t&1)*16384;
    const u16* lb = lsB + (t&1)*16384;
    #pragma unroll
    for (int ks = 0; ks < 2; ++ks) {
      int off = (((4*ks + (l>>4)) ^ (l&7)) << 3);
      bf16x8 af[8], bf_[4];
      #pragma unroll
      for (int fi = 0; fi < 8; ++fi)
        af[fi] = *(const bf16x8*)(la + (wr*128 + fi*16 + (l&15))*64 + off);
      #pragma unroll
      for (int fj = 0; fj < 4; ++fj)
        bf_[fj] = *(const bf16x8*)(lb + (wc*64 + fj*16 + (l&15))*64 + off);
      __builtin_amdgcn_s_setprio(1);
      #pragma unroll
      for (int fi = 0; fi < 8; ++fi)
        #pragma unroll
        for (int fj = 0; fj < 4; ++fj)
          acc[fi][fj] = __builtin_amdgcn_mfma_f32_16x16x32_bf16(af[fi], bf_[fj], acc[fi][fj], 0, 0, 0);
      __builtin_amdgcn_s_setprio(0);
    }
  }
#undef STAGE256

  if (P.mode == 0) {
    int s = n0 / 768;
    int dbase = n0 - s*768 + wc*64;
    const float* bsl = P.bias ? ((s < P.gsplit) ? P.bias + (size_t)s*768
                                                : P.bias2 + (size_t)(s - P.gsplit)*768)
                              : (const float*)0;
    u16* Cs = P.Cb + (size_t)s*P.c_hs;
    #pragma unroll
    for (int fj = 0; fj < 4; ++fj) {
      int dcol = dbase + fj*16 + (l&15);
      float bb = bsl ? bsl[dcol] : 0.f;
      #pragma unroll
      for (int fi = 0; fi < 8; ++fi) {
        #pragma unroll
        for (int r = 0; r < 4; ++r) {
          int row = m0 + wr*128 + fi*16 + (l>>4)*4 + r;
          Cs[(size_t)row*768 + dcol] = f2bf(acc[fi][fj][r] + bb);
        }
      }
    }
  } else if (P.mode == 1) {
    #pragma unroll
    for (int fi = 0; fi < 8; ++fi) {
      #pragma unroll
      for (int r = 0; r < 4; ++r) {
        int row = m0 + wr*128 + fi*16 + (l>>4)*4 + r;
        float bb = P.bias[row];
        #pragma unroll
        for (int fj = 0; fj < 4; ++fj) {
          int cbn = n0 + wc*64 + fj*16 + (l&15);
          P.Cb[(size_t)row*P.ldc + cbn] = f2bf(acc[fi][fj][r] + bb);
        }
      }
    }
  } else {
    // f32 out: mode 2 = store + col bias; mode 3 = accumulate
    #pragma unroll
    for (int fj = 0; fj < 4; ++fj) {
      int col = n0 + wc*64 + fj*16 + (l&15);
      float bb = (P.mode == 2 && P.bias) ? P.bias[col] : 0.f;
      #pragma unroll
      for (int fi = 0; fi < 8; ++fi) {
        #pragma unroll
        for (int r = 0; r < 4; ++r) {
          int row = m0 + wr*128 + fi*16 + (l>>4)*4 + r;
          size_t idx = (size_t)row*P.ldc + col;
          if (P.mode == 2) P.Cf[idx] = acc[fi][fj][r] + bb;
          else             P.Cf[idx] += acc[fi][fj][r];
        }
      }
    }
  }
}

// ---------------- NT GEMM: 128x128 tile (Mt + final output projection) ----------------
__global__ __launch_bounds__(256) void k_gemm(
    const u16* __restrict__ A, long a_hs, int lda,
    const u16* __restrict__ B, long b_hs, int ldb, int K,
    u16* Cb, float* Cf, long c_hs, int ldc,
    const float* __restrict__ bias, const float* __restrict__ bias2,
    long bias_hs, int gsplit, int mode, int swapxy)
{
  __shared__ u16 lsA[3*4096];
  __shared__ u16 lsB[3*4096];
  int g = blockIdx.z;
  const u16* Ag = A + (long)g*a_hs;
  const u16* Bg = B + (long)g*b_hs;
  int tm = swapxy ? blockIdx.y : blockIdx.x;
  int tn = swapxy ? blockIdx.x : blockIdx.y;
  int m0 = tm*128, n0 = tn*128;
  int tid = threadIdx.x;
  int w = tid >> 6, l = tid & 63;

  int srow = l >> 2;
  int scol = ((l & 3) ^ ((l >> 3) & 3)) * 8;
  const u16* ga0 = Ag + (long)(m0 + (2*w)*16   + srow)*lda + scol;
  const u16* ga1 = Ag + (long)(m0 + (2*w+1)*16 + srow)*lda + scol;
  const u16* gb0 = Bg + (long)(n0 + (2*w)*16   + srow)*ldb + scol;
  const u16* gb1 = Bg + (long)(n0 + (2*w+1)*16 + srow)*ldb + scol;

#define GSTAGE(k0, buf) do { \
    gload16(ga0 + (k0), lsA + (buf)*4096 + (2*w)*512); \
    gload16(ga1 + (k0), lsA + (buf)*4096 + (2*w+1)*512); \
    gload16(gb0 + (k0), lsB + (buf)*4096 + (2*w)*512); \
    gload16(gb1 + (k0), lsB + (buf)*4096 + (2*w+1)*512); \
  } while(0)

  f32x4 acc[4][4];
  #pragma unroll
  for (int i = 0; i < 4; ++i)
    #pragma unroll
    for (int j = 0; j < 4; ++j) acc[i][j] = (f32x4)0.0f;

  int wr = w >> 1, wc_ = w & 1;
  int frow = l & 15;
  int sp = (l >> 4) ^ ((frow >> 1) & 3);
  int aoff[4], boff[4];
  #pragma unroll
  for (int i = 0; i < 4; ++i) {
    aoff[i] = (wr*64 + i*16 + frow)*32 + sp*8;
    boff[i] = (wc_*64 + i*16 + frow)*32 + sp*8;
  }

  int nt = K >> 5;
  GSTAGE(0, 0);
  GSTAGE(32, 1);
  VMCNT4; BARRIER;
  int cur = 0;
  for (int t = 0; t < nt; ++t) {
    if (t + 2 < nt) {
      int nb = cur + 2; if (nb >= 3) nb -= 3;
      GSTAGE((t+2) << 5, nb);
    }
    const u16* la = lsA + cur*4096;
    const u16* lb = lsB + cur*4096;
    bf16x8 af[4], bfr[4];
    #pragma unroll
    for (int i = 0; i < 4; ++i) af[i] = *(const bf16x8*)(la + aoff[i]);
    #pragma unroll
    for (int j = 0; j < 4; ++j) bfr[j] = *(const bf16x8*)(lb + boff[j]);
    #pragma unroll
    for (int i = 0; i < 4; ++i)
      #pragma unroll
      for (int j = 0; j < 4; ++j)
        acc[i][j] = __builtin_amdgcn_mfma_f32_16x16x32_bf16(af[i], bfr[j], acc[i][j], 0, 0, 0);
    if (t + 2 < nt) { VMCNT4; } else { VMCNT0; }
    LGKM0; BARRIER;
    cur = (cur == 2) ? 0 : cur + 1;
  }
#undef GSTAGE

  u16* Cbg = Cb ? Cb + (long)g*c_hs : (u16*)0;
  const float* bsel = (g < gsplit) ? bias : bias2;
  long gi = (g < gsplit) ? g : g - gsplit;
  const float* bs = bsel ? bsel + gi*bias_hs : (const float*)0;
  int rl = (l >> 4)*4, cl = l & 15;
  #pragma unroll
  for (int i = 0; i < 4; ++i) {
    #pragma unroll
    for (int j = 0; j < 4; ++j) {
      int rb = m0 + wr*64 + i*16 + rl;
      int cb = n0 + wc_*64 + j*16 + cl;
      float cbv = 0.f;
      if ((mode == 0 || mode == 2) && bs) cbv = bs[cb];
      #pragma unroll
      for (int r = 0; r < 4; ++r) {
        int rr = rb + r;
        float v = acc[i][j][r];
        v += (mode == 1) ? bs[rr] : cbv;
        size_t idx = (size_t)rr*(size_t)ldc + cb;
        if (mode <= 1) Cbg[idx] = f2bf(v);
        else if (mode == 2) Cf[idx] = v;
        else Cf[idx] += v;
      }
    }
  }
}

// ---------------- flash attention (causal), QBLK=64, KBLK=64, 8 waves ----------------
// r10 version (measured best, 134 us): K-operand = xb shared across heads; bias vh.
__global__ __launch_bounds__(512, 2) void k_attn(
    const u16* __restrict__ qb, const u16* __restrict__ xkb,
    const u16* __restrict__ vtb, const float* __restrict__ vh,
    u16* __restrict__ hb, int ldh)
{
  __shared__ u16 kls[3*8192];
  __shared__ u16 vls[3*8192];
  __shared__ float s_t[64*68];
  __shared__ u16 p_t[64*64];
  __shared__ float e_s[64];

  int b = blockIdx.x;
  int xcd = b & 7, kk_ = b >> 3;
  int gn = xcd + 8*(kk_ >> 3), pair = kk_ & 7;
  int g = gn >> 3, n = gn & 7;

  const u16* Q  = qb  + (size_t)g*MROWS*EMB + (size_t)n*SEQ*EMB;
  const u16* Kp = xkb + (size_t)n*SEQ*EMB;
  const u16* Vt = vtb + (size_t)g*EMB*MROWS + (size_t)n*SEQ;
  const float* Vh = vh + (size_t)g*MROWS + (size_t)n*SEQ;
  u16* H = hb + (size_t)(n*SEQ)*ldh + (size_t)g*EMB;

  int tid = threadIdx.x;
  int w = tid >> 6, l = tid & 63;
  int qg = w >> 1;
  int cg = w & 1;
  int frow = l & 15;
  int fsw = frow & 7;
  int srow = tid >> 3;
  int sphys = tid & 7;
  int scol = ((sphys ^ (srow & 7)) << 3);

#define KSTAGE(base, pc, buf) do { \
    gload16((base) + (pc)*128,      kls + (buf)*8192 + w*512); \
    gload16((base) + (pc)*128 + 64, kls + (buf)*8192 + 4096 + w*512); \
  } while(0)
#define VSTAGE(vc, buf) do { \
    gload16(Vs + (size_t)((vc)*128)*MROWS,      vls + (buf)*8192 + w*512); \
    gload16(Vs + (size_t)((vc)*128 + 64)*MROWS, vls + (buf)*8192 + 4096 + w*512); \
  } while(0)

  for (int half = 0; half < 2; ++half) {
    int qt = half ? 15 - pair : pair;
    int q0 = qt * 64;
    int nt = qt + 1;

    f32x4 acc[6][4];
    #pragma unroll
    for (int i = 0; i < 6; ++i)
      #pragma unroll
      for (int j = 0; j < 4; ++j) acc[i][j] = (f32x4)0.0f;
    float m_reg = -1e30f, l_reg = 0.f;

    const u16* Qs = Q + (size_t)(q0 + srow)*EMB + scol;
    bf16x8 qreg[12][2];
    KSTAGE(Qs, 0, 0);
    KSTAGE(Qs, 1, 1);
    VMCNT2; BARRIER;
    #pragma unroll
    for (int pc = 0; pc < 6; ++pc) {
      if (pc < 4) KSTAGE(Qs, pc+2, (pc+2)%3);
      const u16* qb_ = kls + (pc%3)*8192;
      #pragma unroll
      for (int kk2 = 0; kk2 < 2; ++kk2)
        #pragma unroll
        for (int kkl = 0; kkl < 2; ++kkl)
          qreg[2*pc + kk2][kkl] = *(const bf16x8*)(qb_ + kk2*4096 + (qg*16 + frow)*64
                                                   + (((kkl*4 + (l>>4)) ^ fsw) << 3));
      if (pc < 4) { VMCNT2; } else if (pc == 4) { VMCNT0; }
      LGKM0; BARRIER;
    }

    for (int tt = 0; tt < nt; ++tt) {
      int t0 = tt*64;
      const u16* Ks = Kp + (size_t)(t0 + srow)*EMB + scol;
      const u16* Vs = Vt + (size_t)srow*MROWS + t0 + scol;
      float vv0 = Vh[t0 + cg*32 + frow];
      float vv1 = Vh[t0 + cg*32 + 16 + frow];
      if (tt == 0) { KSTAGE(Ks, 0, 0); KSTAGE(Ks, 1, 1); }
      VMCNT2; BARRIER;

      f32x4 sacc[2]; sacc[0] = (f32x4)0.0f; sacc[1] = (f32x4)0.0f;
      #pragma unroll
      for (int c = 0; c < 6; ++c) {
        if (c < 4)       KSTAGE(Ks, c+2, (c+2)%3);
        else if (c == 4) VSTAGE(0, 0);
        else             VSTAGE(1, 1);
        const u16* kb_ = kls + (c%3)*8192;
        __builtin_amdgcn_s_setprio(1);
        #pragma unroll
        for (int kk2 = 0; kk2 < 2; ++kk2) {
          #pragma unroll
          for (int kkl = 0; kkl < 2; ++kkl) {
            int so = ((kkl*4 + (l>>4)) ^ fsw) << 3;
            bf16x8 aq = qreg[2*c + kk2][kkl];
            #pragma unroll
            for (int cc = 0; cc < 2; ++cc) {
              bf16x8 bk_ = *(const bf16x8*)(kb_ + kk2*4096 + ((cg*2 + cc)*16 + frow)*64 + so);
              sacc[cc] = __builtin_amdgcn_mfma_f32_16x16x32_bf16(aq, bk_, sacc[cc], 0, 0, 0);
            }
          }
        }
        __builtin_amdgcn_s_setprio(0);
        if (c < 5) { VMCNT2; LGKM0; BARRIER; }
      }

      #pragma unroll
      for (int r = 0; r < 4; ++r) {
        s_t[(qg*16 + (l>>4)*4 + r)*68 + cg*32 + frow]      = (sacc[0][r] + vv0)*SCALE_S;
        s_t[(qg*16 + (l>>4)*4 + r)*68 + cg*32 + 16 + frow] = (sacc[1][r] + vv1)*SCALE_S;
      }
      LGKM0; BARRIER;
      {
        int qglob = q0 + srow;
        int cbase = t0 + sphys*8;
        float v[8]; float mx = -1e30f;
        #pragma unroll
        for (int j = 0; j < 8; ++j) {
          float s = s_t[srow*68 + sphys*8 + j];
          if (cbase + j > qglob) s = -1e30f;
          v[j] = s; mx = fmaxf(mx, s);
        }
        mx = fmaxf(mx, __shfl_xor(mx, 1));
        mx = fmaxf(mx, __shfl_xor(mx, 2));
        mx = fmaxf(mx, __shfl_xor(mx, 4));
        float mn = fmaxf(m_reg, mx);
        float esc = __expf(m_reg - mn);
        float ps = 0.f; u16 pk[8];
        #pragma unroll
        for (int j = 0; j < 8; ++j) { float p = __expf(v[j] - mn); ps += p; pk[j] = f2bf(p); }
        ps += __shfl_xor(ps, 1); ps += __shfl_xor(ps, 2); ps += __shfl_xor(ps, 4);
        l_reg = l_reg*esc + ps; m_reg = mn;
        if (sphys == 0) e_s[srow] = esc;
        uint4 pv;
        pv.x = (uint32_t)pk[0] | ((uint32_t)pk[1] << 16);
        pv.y = (uint32_t)pk[2] | ((uint32_t)pk[3] << 16);
        pv.z = (uint32_t)pk[4] | ((uint32_t)pk[5] << 16);
        pv.w = (uint32_t)pk[6] | ((uint32_t)pk[7] << 16);
        *(uint4*)(p_t + srow*64 + ((sphys ^ (srow & 7)) << 3)) = pv;
      }
      VMCNT2; LGKM0; BARRIER;
      float er[4];
      #pragma unroll
      for (int r = 0; r < 4; ++r) er[r] = e_s[qg*16 + (l>>4)*4 + r];
      #pragma unroll
      for (int i = 0; i < 6; ++i)
        #pragma unroll
        for (int j = 0; j < 4; ++j)
          #pragma unroll
          for (int r = 0; r < 4; ++r) acc[i][j][r] *= er[r];
      bf16x8 pa[2];
      #pragma unroll
      for (int kk = 0; kk < 2; ++kk)
        pa[kk] = *(const bf16x8*)(p_t + (qg*16 + frow)*64 + (((kk*4 + (l>>4)) ^ fsw) << 3));
      bool stage_next = (tt + 1 < nt);
      const u16* Ks2 = Kp + (size_t)(t0 + 64 + srow)*EMB + scol;
      #pragma unroll
      for (int c = 0; c < 6; ++c) {
        if (c < 4)            VSTAGE(c+2, (c+2)%3);
        else if (stage_next)  { if (c == 4) KSTAGE(Ks2, 0, 0); else KSTAGE(Ks2, 1, 1); }
        const u16* vb_ = vls + (c%3)*8192;
        __builtin_amdgcn_s_setprio(1);
        #pragma unroll
        for (int cf = 0; cf < 4; ++cf) {
          #pragma unroll
          for (int kk = 0; kk < 2; ++kk) {
            bf16x8 vbf = *(const bf16x8*)(vb_ + (cg*64 + cf*16 + frow)*64 + (((kk*4 + (l>>4)) ^ fsw) << 3));
            acc[c][cf] = __builtin_amdgcn_mfma_f32_16x16x32_bf16(pa[kk], vbf, acc[c][cf], 0, 0, 0);
          }
        }
        __builtin_amdgcn_s_setprio(0);
        if (c < 4)      { VMCNT2; LGKM0; BARRIER; }
        else if (c == 4){ if (stage_next) { VMCNT2; } else { VMCNT0; } LGKM0; BARRIER; }
      }
    } // tt
    if (sphys == 0) e_s[srow] = l_reg;
    LGKM0; BARRIER;
    float linv[4];
    #pragma unroll
    for (int r = 0; r < 4; ++r) linv[r] = 1.0f / e_s[qg*16 + (l>>4)*4 + r];
    #pragma unroll
    for (int i = 0; i < 6; ++i)
      #pragma unroll
      for (int j = 0; j < 4; ++j) {
        int col = i*128 + cg*64 + j*16 + (l & 15);
        #pragma unroll
        for (int r = 0; r < 4; ++r) {
          int row = q0 + qg*16 + (l>>4)*4 + r;
          H[(size_t)row*ldh + col] = f2bf(acc[i][j][r]*linv[r]);
        }
      }
    BARRIER;
  } // half
#undef KSTAGE
#undef VSTAGE
}

// ---------------- host ----------------
extern "C" void kernel_launch(void* const* d_in, const int* in_sizes, int n_in,
                              void* d_out, int out_size, void* d_ws, size_t ws_size,
                              hipStream_t stream) {
  const float* x  = (const float*)d_in[0];
  const float* Wq = (const float*)d_in[1];
  const float* bq = (const float*)d_in[2];
  const float* Wk = (const float*)d_in[3];
  const float* bv = (const float*)d_in[6];
  const float* Wv = (const float*)d_in[5];
  const float* Wc = (const float*)d_in[7];
  const float* bc = (const float*)d_in[8];
  float* out = (float*)d_out;
  // bk enters only through a row-constant softmax term -> cancels

  const size_t XB  = (size_t)MROWS*EMB*sizeof(u16);
  const size_t WHB = (size_t)EMB*EMB*sizeof(u16);
  const size_t VHB = (size_t)MROWS*sizeof(float);
  const size_t AB  = (size_t)EMB*sizeof(float);
  const size_t fixed = XB + 36*WHB + 12*(VHB + AB) + 8192;
  int G = 4;
  while (G > 2 && fixed + (size_t)G*3*XB > ws_size) --G;

  char* ws = (char*)d_ws;
  u16* xb  = (u16*)ws;  ws += XB;
  u16* wvb = (u16*)ws;  ws += 12*WHB;
  u16* wcb = (u16*)ws;  ws += 12*WHB;
  u16* mtb = (u16*)ws;  ws += 12*WHB;
  float* vh = (float*)ws; ws += 12*VHB;
  float* ab = (float*)ws; ws += 12*AB;
  u16* yb  = (u16*)ws;  ws += (size_t)G*XB;
  u16* vtb = (u16*)ws;  ws += (size_t)G*XB;
  u16* hbf = (u16*)ws;  ws += (size_t)G*XB;
  // one-time transposed-weight scratch aliases hbf (wqT) and vtb (wkT)
  u16* wqT = hbf;
  u16* wkT = vtb;

  // ---- one-time prep (all 12 heads) ----
  k_cvt<<<dim3(3072), dim3(256), 0, stream>>>(x, xb, (long)MROWS*EMB);
  k_cvtT<<<dim3(12, 12, 24), dim3(256), 0, stream>>>(Wq, Wk, wqT, wkT, 12);
  k_cvt<<<dim3((unsigned)((12L*EMB*EMB/8)/256)), dim3(256), 0, stream>>>(
      Wv, wvb, 12L*EMB*EMB);
  k_cvtwc<<<dim3((unsigned)((768L*12*EMB/4)/256)), dim3(256), 0, stream>>>(Wc, wcb, 12, 0);
  k_gemm<<<dim3(6, 6, 12), dim3(256), 0, stream>>>(
      wkT, (long)EMB*EMB, EMB, wqT, (long)EMB*EMB, EMB, EMB,
      mtb, (float*)0, (long)EMB*EMB, EMB,
      (const float*)0, (const float*)0, 0L, 9999, 0, 0);
  k_mka<<<dim3(3, 12), dim3(256), 0, stream>>>(wkT, bq, ab);
  k_mkv<<<dim3(1024, 12), dim3(512), 0, stream>>>(xb, ab, vh);

  int h_prev = -1, Gi_prev = 0;
  for (int h0 = 0; h0 < NHEAD; h0 += G) {
    int Gi = (G < NHEAD - h0) ? G : (NHEAD - h0);
    // plane 0: y = x*Mt^T (sliced bf16); plane 1: Vt = Wv*x^T + bv;
    // plane 2 (if prev group exists): out (+)= hbf_prev * Wc_prev^T
    Gemm256Args ay; Gemm256Args av; Gemm256Args ap;
    ay.A = xb; ay.lda = EMB; ay.B = mtb + (size_t)h0*EMB*EMB; ay.ldb = EMB; ay.K = EMB;
    ay.Cb = yb; ay.Cf = 0; ay.c_hs = (long)MROWS*EMB; ay.ldc = 768;
    ay.bias = 0; ay.bias2 = 0; ay.gsplit = Gi; ay.mode = 0; ay.swap = 0; ay.ny = 3*Gi;
    av.A = wvb + (size_t)h0*EMB*EMB; av.lda = EMB; av.B = xb; av.ldb = EMB; av.K = EMB;
    av.Cb = vtb; av.Cf = 0; av.c_hs = 0; av.ldc = MROWS;
    av.bias = bv + (size_t)h0*EMB; av.bias2 = 0; av.gsplit = 9999; av.mode = 1;
    av.swap = 1; av.ny = 3*Gi;
    ap.A = 0; ap.lda = 0; ap.B = 0; ap.ldb = 0; ap.K = 64; ap.Cb = 0; ap.Cf = 0;
    ap.c_hs = 0; ap.ldc = 0; ap.bias = 0; ap.bias2 = 0; ap.gsplit = 0; ap.mode = 3;
    ap.swap = 0; ap.ny = 0;
    if (h_prev >= 0) {
      ap.A = hbf; ap.lda = Gi_prev*EMB;
      ap.B = wcb + (size_t)h_prev*EMB; ap.ldb = NHEAD*EMB; ap.K = Gi_prev*EMB;
      ap.Cf = out; ap.ldc = EMB;
      ap.bias = (h_prev == 0) ? bc : (const float*)0;
      ap.mode = (h_prev == 0) ? 2 : 3;
      ap.ny = 3;
    }
    k_gemm256t<<<dim3(32, ay.ny + av.ny + ap.ny), dim3(512), 0, stream>>>(ay, av, ap);
    // flash attention (K = xb) -> hbf [8192, Gi*768]
    k_attn<<<dim3(8*NBAT*Gi), dim3(512), 0, stream>>>(
        yb, xb, vtb, vh + (size_t)h0*MROWS, hbf, Gi*EMB);
    h_prev = h0; Gi_prev = Gi;
  }
  // final group's projection (standalone 128^2 kernel, 384 blocks)
  k_gemm<<<dim3(64, 6, 1), dim3(256), 0, stream>>>(
      hbf, 0L, Gi_prev*EMB, wcb + (size_t)h_prev*EMB, 0L, NHEAD*EMB, Gi_prev*EMB,
      (u16*)0, out, 0L, EMB,
      (h_prev == 0 ? bc : (const float*)0), (const float*)0, 0L, 9999,
      (h_prev == 0 ? 2 : 3), 0);
}

// Round 14
// 1006.289 us; speedup vs baseline: 1.1316x; 1.0497x over previous
//
#include <hip/hip_runtime.h>
#include <hip/hip_bf16.h>
#include <stdint.h>

#define SEQ    1024
#define NBAT   8
#define EMB    768
#define NHEAD  12
#define MROWS  (NBAT*SEQ)            // 8192
#define SCALE_S 0.03608439182435161f // 1/sqrt(768)

typedef unsigned short u16;
typedef __attribute__((ext_vector_type(8))) short bf16x8;
typedef __attribute__((ext_vector_type(4))) float f32x4;

typedef void __attribute__((address_space(1)))* gas_ptr;
typedef void __attribute__((address_space(3)))* las_ptr;

__device__ __forceinline__ void gload16(const void* g, void* l) {
  __builtin_amdgcn_global_load_lds((gas_ptr)(void*)g, (las_ptr)l, 16, 0, 0);
}

#define VMCNT0 asm volatile("s_waitcnt vmcnt(0)" ::: "memory")
#define VMCNT2 asm volatile("s_waitcnt vmcnt(2)" ::: "memory")
#define VMCNT4 asm volatile("s_waitcnt vmcnt(4)" ::: "memory")
#define LGKM0  asm volatile("s_waitcnt lgkmcnt(0)" ::: "memory")
#define BARRIER asm volatile("s_barrier" ::: "memory")

__device__ __forceinline__ u16 f2bf(float f) {
  union { float f; uint32_t u; } a; a.f = f;
  uint32_t r = a.u + 0x7fffu + ((a.u >> 16) & 1u);
  return (u16)(r >> 16);
}
__device__ __forceinline__ float bf2f(u16 b) {
  union { uint32_t u; float f; } c; c.u = (uint32_t)b << 16; return c.f;
}
__device__ __forceinline__ uint32_t pack2(float a, float b) {
  return (uint32_t)f2bf(a) | ((uint32_t)f2bf(b) << 16);
}

// ---------------- conversion / prep kernels ----------------
__global__ void k_cvt(const float* __restrict__ s, u16* __restrict__ d, long n) {
  long i = ((long)blockIdx.x*blockDim.x + threadIdx.x)*8;
  if (i >= n) return;
  float4 a = *(const float4*)(s+i);
  float4 b = *(const float4*)(s+i+4);
  uint4 o; o.x = pack2(a.x,a.y); o.y = pack2(a.z,a.w);
  o.z = pack2(b.x,b.y); o.w = pack2(b.z,b.w);
  *(uint4*)(d+i) = o;
}

// transpose-convert: f32 [768][768] (row=d) -> bf16 [768][768] (row=e)
__global__ void k_cvtT(const float* __restrict__ wq, const float* __restrict__ wk,
                       u16* __restrict__ dq, u16* __restrict__ dk, int Gi) {
  __shared__ float t[64][65];
  int z = blockIdx.z;
  const float* src = (z < Gi) ? wq + (size_t)z*EMB*EMB : wk + (size_t)(z-Gi)*EMB*EMB;
  u16* dst = (z < Gi) ? dq + (size_t)z*EMB*EMB : dk + (size_t)(z-Gi)*EMB*EMB;
  int d0 = blockIdx.x*64, e0 = blockIdx.y*64;
  int tt = threadIdx.x;
  int el = tt & 63, db = tt >> 6;
  #pragma unroll
  for (int p = 0; p < 16; ++p) {
    int dl = p*4 + db;
    t[dl][el] = src[(size_t)(d0+dl)*EMB + e0 + el];
  }
  __syncthreads();
  int dl2 = tt & 63, eb = tt >> 6;
  #pragma unroll
  for (int p = 0; p < 16; ++p) {
    int e2 = p*4 + eb;
    dst[(size_t)(e0+e2)*EMB + d0 + dl2] = f2bf(t[dl2][e2]);
  }
}

// convert full Wc [768, 9216] -> bf16
__global__ void k_cvtwc(const float* __restrict__ wc, u16* __restrict__ d, int Gi, int h0) {
  long ncol = (long)Gi*EMB;
  long i = ((long)blockIdx.x*blockDim.x + threadIdx.x)*4;
  if (i >= 768*ncol) return;
  long eo = i / ncol, c = i - eo*ncol;
  long g = c / EMB, dd = c - g*EMB;
  const float* s = wc + eo*(long)(NHEAD*EMB) + (h0+g)*EMB + dd;
  float4 a = *(const float4*)s;
  uint2 o; o.x = pack2(a.x,a.y); o.y = pack2(a.z,a.w);
  *(uint2*)(d+i) = o;
}

// a[g][e] = sum_d Wk[d][e]*bq[d]  — wave per output element
__global__ void k_mka(const u16* __restrict__ wkT, const float* __restrict__ bq,
                      float* __restrict__ a) {
  int g = blockIdx.y;
  int w = threadIdx.x >> 6, l = threadIdx.x & 63;
  int e = blockIdx.x*4 + w;
  const u16* row = wkT + (size_t)g*EMB*EMB + (size_t)e*EMB;
  const float* b = bq + (size_t)g*EMB;
  float s = 0.f;
  #pragma unroll
  for (int c = 0; c < 12; ++c) {
    int d = c*64 + l;
    s += bf2f(row[d]) * b[d];
  }
  s += __shfl_xor(s, 1); s += __shfl_xor(s, 2); s += __shfl_xor(s, 4);
  s += __shfl_xor(s, 8); s += __shfl_xor(s, 16); s += __shfl_xor(s, 32);
  if (l == 0) a[(size_t)g*EMB + e] = s;
}

// v[g][i] = sum_e xb[i][e]*a[g][e] — wave per row, single x pass, loop g in-reg
__global__ void k_mkv(const u16* __restrict__ xb, const float* __restrict__ a,
                      float* __restrict__ v) {
  int w = threadIdx.x >> 6, l = threadIdx.x & 63;
  int i = blockIdx.x*8 + w;
  const u16* xr = xb + (size_t)i*EMB;
  float xv[12];
  #pragma unroll
  for (int c = 0; c < 12; ++c) xv[c] = bf2f(xr[c*64 + l]);
  for (int g = 0; g < NHEAD; ++g) {
    const float* ag = a + (size_t)g*EMB;
    float s = 0.f;
    #pragma unroll
    for (int c = 0; c < 12; ++c) s += xv[c] * ag[c*64 + l];
    s += __shfl_xor(s, 1); s += __shfl_xor(s, 2); s += __shfl_xor(s, 4);
    s += __shfl_xor(s, 8); s += __shfl_xor(s, 16); s += __shfl_xor(s, 32);
    if (l == 0) v[(size_t)g*MROWS + i] = s;
  }
}

// ---------------- dual 256x256 NT GEMM (r4 structure; two configs per launch) ----------------
struct Gemm256Args {
  const u16* A; int lda;
  const u16* B; int ldb; int K;
  u16* Cb; long c_hs; int ldc;
  const float* bias; const float* bias2;
  int gsplit; int mode; int swap;
};

__global__ __launch_bounds__(512, 2) void k_gemm256d(Gemm256Args p0, Gemm256Args p1)
{
  __shared__ u16 lsA[2*16384];
  __shared__ u16 lsB[2*16384];

  const Gemm256Args P = blockIdx.z ? p1 : p0;
  int m0 = (P.swap ? blockIdx.y : blockIdx.x) * 256;
  int n0 = (P.swap ? blockIdx.x : blockIdx.y) * 256;
  int tid = threadIdx.x;
  int w = tid >> 6, l = tid & 63;
  int wr = w >> 2, wc = w & 3;

  const u16* gA = P.A + (size_t)(m0 + 32*w + (l>>3))*P.lda + (((l&7) ^ (l>>3)) << 3);
  const u16* gB = P.B + (size_t)(n0 + 32*w + (l>>3))*P.ldb + (((l&7) ^ (l>>3)) << 3);

#define STAGE256(t, buf) do { \
    int k0_ = (t)*64; \
    _Pragma("unroll") \
    for (int c_ = 0; c_ < 4; ++c_) \
      gload16(gA + (size_t)(c_*8)*P.lda + k0_, lsA + (buf)*16384 + (32*w + 8*c_)*64); \
    _Pragma("unroll") \
    for (int c_ = 0; c_ < 4; ++c_) \
      gload16(gB + (size_t)(c_*8)*P.ldb + k0_, lsB + (buf)*16384 + (32*w + 8*c_)*64); \
  } while(0)

  f32x4 acc[8][4];
  #pragma unroll
  for (int i = 0; i < 8; ++i)
    #pragma unroll
    for (int j = 0; j < 4; ++j) acc[i][j] = (f32x4)0.0f;

  int nt = P.K >> 6;
  STAGE256(0, 0);
  for (int t = 0; t < nt; ++t) {
    VMCNT0; BARRIER;
    if (t + 1 < nt) STAGE256(t+1, (t+1)&1);
    const u16* la = lsA + (t&1)*16384;
    const u16* lb = lsB + (t&1)*16384;
    #pragma unroll
    for (int ks = 0; ks < 2; ++ks) {
      int off = (((4*ks + (l>>4)) ^ (l&7)) << 3);
      bf16x8 af[8], bf_[4];
      #pragma unroll
      for (int fi = 0; fi < 8; ++fi)
        af[fi] = *(const bf16x8*)(la + (wr*128 + fi*16 + (l&15))*64 + off);
      #pragma unroll
      for (int fj = 0; fj < 4; ++fj)
        bf_[fj] = *(const bf16x8*)(lb + (wc*64 + fj*16 + (l&15))*64 + off);
      __builtin_amdgcn_s_setprio(1);
      #pragma unroll
      for (int fi = 0; fi < 8; ++fi)
        #pragma unroll
        for (int fj = 0; fj < 4; ++fj)
          acc[fi][fj] = __builtin_amdgcn_mfma_f32_16x16x32_bf16(af[fi], bf_[fj], acc[fi][fj], 0, 0, 0);
      __builtin_amdgcn_s_setprio(0);
    }
  }
#undef STAGE256

  if (P.mode == 0) {
    int s = n0 / 768;
    int dbase = n0 - s*768 + wc*64;
    const float* bsl = P.bias ? ((s < P.gsplit) ? P.bias + (size_t)s*768
                                                : P.bias2 + (size_t)(s - P.gsplit)*768)
                              : (const float*)0;
    u16* Cs = P.Cb + (size_t)s*P.c_hs;
    #pragma unroll
    for (int fj = 0; fj < 4; ++fj) {
      int dcol = dbase + fj*16 + (l&15);
      float bb = bsl ? bsl[dcol] : 0.f;
      #pragma unroll
      for (int fi = 0; fi < 8; ++fi) {
        #pragma unroll
        for (int r = 0; r < 4; ++r) {
          int row = m0 + wr*128 + fi*16 + (l>>4)*4 + r;
          Cs[(size_t)row*768 + dcol] = f2bf(acc[fi][fj][r] + bb);
        }
      }
    }
  } else {
    #pragma unroll
    for (int fi = 0; fi < 8; ++fi) {
      #pragma unroll
      for (int r = 0; r < 4; ++r) {
        int row = m0 + wr*128 + fi*16 + (l>>4)*4 + r;
        float bb = P.bias[row];
        #pragma unroll
        for (int fj = 0; fj < 4; ++fj) {
          int cbn = n0 + wc*64 + fj*16 + (l&15);
          P.Cb[(size_t)row*P.ldc + cbn] = f2bf(acc[fi][fj][r] + bb);
        }
      }
    }
  }
}

// ---------------- NT GEMM: 128x128 tile (Mt + output projection) ----------------
__global__ __launch_bounds__(256) void k_gemm(
    const u16* __restrict__ A, long a_hs, int lda,
    const u16* __restrict__ B, long b_hs, int ldb, int K,
    u16* Cb, float* Cf, long c_hs, int ldc,
    const float* __restrict__ bias, const float* __restrict__ bias2,
    long bias_hs, int gsplit, int mode, int swapxy)
{
  __shared__ u16 lsA[3*4096];
  __shared__ u16 lsB[3*4096];
  int g = blockIdx.z;
  const u16* Ag = A + (long)g*a_hs;
  const u16* Bg = B + (long)g*b_hs;
  int tm = swapxy ? blockIdx.y : blockIdx.x;
  int tn = swapxy ? blockIdx.x : blockIdx.y;
  int m0 = tm*128, n0 = tn*128;
  int tid = threadIdx.x;
  int w = tid >> 6, l = tid & 63;

  int srow = l >> 2;
  int scol = ((l & 3) ^ ((l >> 3) & 3)) * 8;
  const u16* ga0 = Ag + (long)(m0 + (2*w)*16   + srow)*lda + scol;
  const u16* ga1 = Ag + (long)(m0 + (2*w+1)*16 + srow)*lda + scol;
  const u16* gb0 = Bg + (long)(n0 + (2*w)*16   + srow)*ldb + scol;
  const u16* gb1 = Bg + (long)(n0 + (2*w+1)*16 + srow)*ldb + scol;

#define GSTAGE(k0, buf) do { \
    gload16(ga0 + (k0), lsA + (buf)*4096 + (2*w)*512); \
    gload16(ga1 + (k0), lsA + (buf)*4096 + (2*w+1)*512); \
    gload16(gb0 + (k0), lsB + (buf)*4096 + (2*w)*512); \
    gload16(gb1 + (k0), lsB + (buf)*4096 + (2*w+1)*512); \
  } while(0)

  f32x4 acc[4][4];
  #pragma unroll
  for (int i = 0; i < 4; ++i)
    #pragma unroll
    for (int j = 0; j < 4; ++j) acc[i][j] = (f32x4)0.0f;

  int wr = w >> 1, wc_ = w & 1;
  int frow = l & 15;
  int sp = (l >> 4) ^ ((frow >> 1) & 3);
  int aoff[4], boff[4];
  #pragma unroll
  for (int i = 0; i < 4; ++i) {
    aoff[i] = (wr*64 + i*16 + frow)*32 + sp*8;
    boff[i] = (wc_*64 + i*16 + frow)*32 + sp*8;
  }

  int nt = K >> 5;
  GSTAGE(0, 0);
  GSTAGE(32, 1);
  VMCNT4; BARRIER;
  int cur = 0;
  for (int t = 0; t < nt; ++t) {
    if (t + 2 < nt) {
      int nb = cur + 2; if (nb >= 3) nb -= 3;
      GSTAGE((t+2) << 5, nb);
    }
    const u16* la = lsA + cur*4096;
    const u16* lb = lsB + cur*4096;
    bf16x8 af[4], bfr[4];
    #pragma unroll
    for (int i = 0; i < 4; ++i) af[i] = *(const bf16x8*)(la + aoff[i]);
    #pragma unroll
    for (int j = 0; j < 4; ++j) bfr[j] = *(const bf16x8*)(lb + boff[j]);
    #pragma unroll
    for (int i = 0; i < 4; ++i)
      #pragma unroll
      for (int j = 0; j < 4; ++j)
        acc[i][j] = __builtin_amdgcn_mfma_f32_16x16x32_bf16(af[i], bfr[j], acc[i][j], 0, 0, 0);
    if (t + 2 < nt) { VMCNT4; } else { VMCNT0; }
    LGKM0; BARRIER;
    cur = (cur == 2) ? 0 : cur + 1;
  }
#undef GSTAGE

  u16* Cbg = Cb ? Cb + (long)g*c_hs : (u16*)0;
  const float* bsel = (g < gsplit) ? bias : bias2;
  long gi = (g < gsplit) ? g : g - gsplit;
  const float* bs = bsel ? bsel + gi*bias_hs : (const float*)0;
  int rl = (l >> 4)*4, cl = l & 15;
  #pragma unroll
  for (int i = 0; i < 4; ++i) {
    #pragma unroll
    for (int j = 0; j < 4; ++j) {
      int rb = m0 + wr*64 + i*16 + rl;
      int cb = n0 + wc_*64 + j*16 + cl;
      float cbv = 0.f;
      if ((mode == 0 || mode == 2) && bs) cbv = bs[cb];
      #pragma unroll
      for (int r = 0; r < 4; ++r) {
        int rr = rb + r;
        float v = acc[i][j][r];
        v += (mode == 1) ? bs[rr] : cbv;
        size_t idx = (size_t)rr*(size_t)ldc + cb;
        if (mode <= 1) Cbg[idx] = f2bf(v);
        else if (mode == 2) Cf[idx] = v;
        else Cf[idx] += v;
      }
    }
  }
}

// ---------------- flash attention (causal), QBLK=64, KBLK=64, 8 waves ----------------
// r10 version (measured best, 134 us): K-operand = xb shared across heads; bias vh.
__global__ __launch_bounds__(512, 2) void k_attn(
    const u16* __restrict__ qb, const u16* __restrict__ xkb,
    const u16* __restrict__ vtb, const float* __restrict__ vh,
    u16* __restrict__ hb, int ldh)
{
  __shared__ u16 kls[3*8192];
  __shared__ u16 vls[3*8192];
  __shared__ float s_t[64*68];
  __shared__ u16 p_t[64*64];
  __shared__ float e_s[64];

  int b = blockIdx.x;
  int xcd = b & 7, kk_ = b >> 3;
  int gn = xcd + 8*(kk_ >> 3), pair = kk_ & 7;
  int g = gn >> 3, n = gn & 7;

  const u16* Q  = qb  + (size_t)g*MROWS*EMB + (size_t)n*SEQ*EMB;
  const u16* Kp = xkb + (size_t)n*SEQ*EMB;
  const u16* Vt = vtb + (size_t)g*EMB*MROWS + (size_t)n*SEQ;
  const float* Vh = vh + (size_t)g*MROWS + (size_t)n*SEQ;
  u16* H = hb + (size_t)(n*SEQ)*ldh + (size_t)g*EMB;

  int tid = threadIdx.x;
  int w = tid >> 6, l = tid & 63;
  int qg = w >> 1;
  int cg = w & 1;
  int frow = l & 15;
  int fsw = frow & 7;
  int srow = tid >> 3;
  int sphys = tid & 7;
  int scol = ((sphys ^ (srow & 7)) << 3);

#define KSTAGE(base, pc, buf) do { \
    gload16((base) + (pc)*128,      kls + (buf)*8192 + w*512); \
    gload16((base) + (pc)*128 + 64, kls + (buf)*8192 + 4096 + w*512); \
  } while(0)
#define VSTAGE(vc, buf) do { \
    gload16(Vs + (size_t)((vc)*128)*MROWS,      vls + (buf)*8192 + w*512); \
    gload16(Vs + (size_t)((vc)*128 + 64)*MROWS, vls + (buf)*8192 + 4096 + w*512); \
  } while(0)

  for (int half = 0; half < 2; ++half) {
    int qt = half ? 15 - pair : pair;
    int q0 = qt * 64;
    int nt = qt + 1;

    f32x4 acc[6][4];
    #pragma unroll
    for (int i = 0; i < 6; ++i)
      #pragma unroll
      for (int j = 0; j < 4; ++j) acc[i][j] = (f32x4)0.0f;
    float m_reg = -1e30f, l_reg = 0.f;

    const u16* Qs = Q + (size_t)(q0 + srow)*EMB + scol;
    bf16x8 qreg[12][2];
    KSTAGE(Qs, 0, 0);
    KSTAGE(Qs, 1, 1);
    VMCNT2; BARRIER;
    #pragma unroll
    for (int pc = 0; pc < 6; ++pc) {
      if (pc < 4) KSTAGE(Qs, pc+2, (pc+2)%3);
      const u16* qb_ = kls + (pc%3)*8192;
      #pragma unroll
      for (int kk2 = 0; kk2 < 2; ++kk2)
        #pragma unroll
        for (int kkl = 0; kkl < 2; ++kkl)
          qreg[2*pc + kk2][kkl] = *(const bf16x8*)(qb_ + kk2*4096 + (qg*16 + frow)*64
                                                   + (((kkl*4 + (l>>4)) ^ fsw) << 3));
      if (pc < 4) { VMCNT2; } else if (pc == 4) { VMCNT0; }
      LGKM0; BARRIER;
    }

    for (int tt = 0; tt < nt; ++tt) {
      int t0 = tt*64;
      const u16* Ks = Kp + (size_t)(t0 + srow)*EMB + scol;
      const u16* Vs = Vt + (size_t)srow*MROWS + t0 + scol;
      float vv0 = Vh[t0 + cg*32 + frow];
      float vv1 = Vh[t0 + cg*32 + 16 + frow];
      if (tt == 0) { KSTAGE(Ks, 0, 0); KSTAGE(Ks, 1, 1); }
      VMCNT2; BARRIER;

      f32x4 sacc[2]; sacc[0] = (f32x4)0.0f; sacc[1] = (f32x4)0.0f;
      #pragma unroll
      for (int c = 0; c < 6; ++c) {
        if (c < 4)       KSTAGE(Ks, c+2, (c+2)%3);
        else if (c == 4) VSTAGE(0, 0);
        else             VSTAGE(1, 1);
        const u16* kb_ = kls + (c%3)*8192;
        __builtin_amdgcn_s_setprio(1);
        #pragma unroll
        for (int kk2 = 0; kk2 < 2; ++kk2) {
          #pragma unroll
          for (int kkl = 0; kkl < 2; ++kkl) {
            int so = ((kkl*4 + (l>>4)) ^ fsw) << 3;
            bf16x8 aq = qreg[2*c + kk2][kkl];
            #pragma unroll
            for (int cc = 0; cc < 2; ++cc) {
              bf16x8 bk_ = *(const bf16x8*)(kb_ + kk2*4096 + ((cg*2 + cc)*16 + frow)*64 + so);
              sacc[cc] = __builtin_amdgcn_mfma_f32_16x16x32_bf16(aq, bk_, sacc[cc], 0, 0, 0);
            }
          }
        }
        __builtin_amdgcn_s_setprio(0);
        if (c < 5) { VMCNT2; LGKM0; BARRIER; }
      }

      #pragma unroll
      for (int r = 0; r < 4; ++r) {
        s_t[(qg*16 + (l>>4)*4 + r)*68 + cg*32 + frow]      = (sacc[0][r] + vv0)*SCALE_S;
        s_t[(qg*16 + (l>>4)*4 + r)*68 + cg*32 + 16 + frow] = (sacc[1][r] + vv1)*SCALE_S;
      }
      LGKM0; BARRIER;
      {
        int qglob = q0 + srow;
        int cbase = t0 + sphys*8;
        float v[8]; float mx = -1e30f;
        #pragma unroll
        for (int j = 0; j < 8; ++j) {
          float s = s_t[srow*68 + sphys*8 + j];
          if (cbase + j > qglob) s = -1e30f;
          v[j] = s; mx = fmaxf(mx, s);
        }
        mx = fmaxf(mx, __shfl_xor(mx, 1));
        mx = fmaxf(mx, __shfl_xor(mx, 2));
        mx = fmaxf(mx, __shfl_xor(mx, 4));
        float mn = fmaxf(m_reg, mx);
        float esc = __expf(m_reg - mn);
        float ps = 0.f; u16 pk[8];
        #pragma unroll
        for (int j = 0; j < 8; ++j) { float p = __expf(v[j] - mn); ps += p; pk[j] = f2bf(p); }
        ps += __shfl_xor(ps, 1); ps += __shfl_xor(ps, 2); ps += __shfl_xor(ps, 4);
        l_reg = l_reg*esc + ps; m_reg = mn;
        if (sphys == 0) e_s[srow] = esc;
        uint4 pv;
        pv.x = (uint32_t)pk[0] | ((uint32_t)pk[1] << 16);
        pv.y = (uint32_t)pk[2] | ((uint32_t)pk[3] << 16);
        pv.z = (uint32_t)pk[4] | ((uint32_t)pk[5] << 16);
        pv.w = (uint32_t)pk[6] | ((uint32_t)pk[7] << 16);
        *(uint4*)(p_t + srow*64 + ((sphys ^ (srow & 7)) << 3)) = pv;
      }
      VMCNT2; LGKM0; BARRIER;
      float er[4];
      #pragma unroll
      for (int r = 0; r < 4; ++r) er[r] = e_s[qg*16 + (l>>4)*4 + r];
      #pragma unroll
      for (int i = 0; i < 6; ++i)
        #pragma unroll
        for (int j = 0; j < 4; ++j)
          #pragma unroll
          for (int r = 0; r < 4; ++r) acc[i][j][r] *= er[r];
      bf16x8 pa[2];
      #pragma unroll
      for (int kk = 0; kk < 2; ++kk)
        pa[kk] = *(const bf16x8*)(p_t + (qg*16 + frow)*64 + (((kk*4 + (l>>4)) ^ fsw) << 3));
      bool stage_next = (tt + 1 < nt);
      const u16* Ks2 = Kp + (size_t)(t0 + 64 + srow)*EMB + scol;
      #pragma unroll
      for (int c = 0; c < 6; ++c) {
        if (c < 4)            VSTAGE(c+2, (c+2)%3);
        else if (stage_next)  { if (c == 4) KSTAGE(Ks2, 0, 0); else KSTAGE(Ks2, 1, 1); }
        const u16* vb_ = vls + (c%3)*8192;
        __builtin_amdgcn_s_setprio(1);
        #pragma unroll
        for (int cf = 0; cf < 4; ++cf) {
          #pragma unroll
          for (int kk = 0; kk < 2; ++kk) {
            bf16x8 vbf = *(const bf16x8*)(vb_ + (cg*64 + cf*16 + frow)*64 + (((kk*4 + (l>>4)) ^ fsw) << 3));
            acc[c][cf] = __builtin_amdgcn_mfma_f32_16x16x32_bf16(pa[kk], vbf, acc[c][cf], 0, 0, 0);
          }
        }
        __builtin_amdgcn_s_setprio(0);
        if (c < 4)      { VMCNT2; LGKM0; BARRIER; }
        else if (c == 4){ if (stage_next) { VMCNT2; } else { VMCNT0; } LGKM0; BARRIER; }
      }
    } // tt
    if (sphys == 0) e_s[srow] = l_reg;
    LGKM0; BARRIER;
    float linv[4];
    #pragma unroll
    for (int r = 0; r < 4; ++r) linv[r] = 1.0f / e_s[qg*16 + (l>>4)*4 + r];
    #pragma unroll
    for (int i = 0; i < 6; ++i)
      #pragma unroll
      for (int j = 0; j < 4; ++j) {
        int col = i*128 + cg*64 + j*16 + (l & 15);
        #pragma unroll
        for (int r = 0; r < 4; ++r) {
          int row = q0 + qg*16 + (l>>4)*4 + r;
          H[(size_t)row*ldh + col] = f2bf(acc[i][j][r]*linv[r]);
        }
      }
    BARRIER;
  } // half
#undef KSTAGE
#undef VSTAGE
}

// ---------------- host ----------------
extern "C" void kernel_launch(void* const* d_in, const int* in_sizes, int n_in,
                              void* d_out, int out_size, void* d_ws, size_t ws_size,
                              hipStream_t stream) {
  const float* x  = (const float*)d_in[0];
  const float* Wq = (const float*)d_in[1];
  const float* bq = (const float*)d_in[2];
  const float* Wk = (const float*)d_in[3];
  const float* bv = (const float*)d_in[6];
  const float* Wv = (const float*)d_in[5];
  const float* Wc = (const float*)d_in[7];
  const float* bc = (const float*)d_in[8];
  float* out = (float*)d_out;
  // bk enters only through a row-constant softmax term -> cancels

  const size_t XB  = (size_t)MROWS*EMB*sizeof(u16);
  const size_t WHB = (size_t)EMB*EMB*sizeof(u16);
  const size_t VHB = (size_t)MROWS*sizeof(float);
  const size_t AB  = (size_t)EMB*sizeof(float);
  const size_t fixed = XB + 36*WHB + 12*(VHB + AB) + 8192;
  int G = 4;
  while (G > 2 && fixed + (size_t)G*3*XB > ws_size) --G;

  char* ws = (char*)d_ws;
  u16* xb  = (u16*)ws;  ws += XB;
  u16* wvb = (u16*)ws;  ws += 12*WHB;
  u16* wcb = (u16*)ws;  ws += 12*WHB;
  u16* mtb = (u16*)ws;  ws += 12*WHB;
  float* vh = (float*)ws; ws += 12*VHB;
  float* ab = (float*)ws; ws += 12*AB;
  u16* yb  = (u16*)ws;  ws += (size_t)G*XB;
  u16* vtb = (u16*)ws;  ws += (size_t)G*XB;
  u16* hbf = (u16*)ws;  ws += (size_t)G*XB;
  // one-time transposed-weight scratch aliases hbf (wqT) and vtb (wkT)
  u16* wqT = hbf;
  u16* wkT = vtb;

  // ---- one-time prep (all 12 heads) ----
  k_cvt<<<dim3(3072), dim3(256), 0, stream>>>(x, xb, (long)MROWS*EMB);
  k_cvtT<<<dim3(12, 12, 24), dim3(256), 0, stream>>>(Wq, Wk, wqT, wkT, 12);
  k_cvt<<<dim3((unsigned)((12L*EMB*EMB/8)/256)), dim3(256), 0, stream>>>(
      Wv, wvb, 12L*EMB*EMB);
  k_cvtwc<<<dim3((unsigned)((768L*12*EMB/4)/256)), dim3(256), 0, stream>>>(Wc, wcb, 12, 0);
  k_gemm<<<dim3(6, 6, 12), dim3(256), 0, stream>>>(
      wkT, (long)EMB*EMB, EMB, wqT, (long)EMB*EMB, EMB, EMB,
      mtb, (float*)0, (long)EMB*EMB, EMB,
      (const float*)0, (const float*)0, 0L, 9999, 0, 0);
  k_mka<<<dim3(192, 12), dim3(256), 0, stream>>>(wkT, bq, ab);
  k_mkv<<<dim3(1024), dim3(512), 0, stream>>>(xb, ab, vh);

  for (int h0 = 0; h0 < NHEAD; h0 += G) {
    int Gi = (G < NHEAD - h0) ? G : (NHEAD - h0);
    // fused launch: z=0 -> y = x*Mt^T (sliced bf16), z=1 -> Vt = Wv*x^T + bv
    Gemm256Args ay = { xb, EMB, mtb + (size_t)h0*EMB*EMB, EMB, EMB,
                       yb, (long)MROWS*EMB, 768,
                       (const float*)0, (const float*)0, Gi, 0, 0 };
    Gemm256Args av = { wvb + (size_t)h0*EMB*EMB, EMB, xb, EMB, EMB,
                       vtb, 0L, MROWS,
                       bv + (size_t)h0*EMB, (const float*)0, 9999, 1, 1 };
    k_gemm256d<<<dim3(32, 3*Gi, 2), dim3(512), 0, stream>>>(ay, av);
    // flash attention (K = xb) -> hbf [8192, Gi*768]
    k_attn<<<dim3(8*NBAT*Gi), dim3(512), 0, stream>>>(
        yb, xb, vtb, vh + (size_t)h0*MROWS, hbf, Gi*EMB);
    // out += heads_group * Wc_group^T (+bc on first group)
    k_gemm<<<dim3(64, 6, 1), dim3(256), 0, stream>>>(
        hbf, 0L, Gi*EMB, wcb + (size_t)h0*EMB, 0L, NHEAD*EMB, Gi*EMB,
        (u16*)0, out, 0L, EMB,
        (h0 == 0 ? bc : (const float*)0), (const float*)0, 0L, 9999,
        (h0 == 0 ? 2 : 3), 0);
  }
}

// Round 15
// 1002.354 us; speedup vs baseline: 1.1360x; 1.0039x over previous
//
#include <hip/hip_runtime.h>
#include <hip/hip_bf16.h>
#include <stdint.h>

#define SEQ    1024
#define NBAT   8
#define EMB    768
#define NHEAD  12
#define MROWS  (NBAT*SEQ)            // 8192
#define SCALE_S 0.03608439182435161f // 1/sqrt(768)

typedef unsigned short u16;
typedef __attribute__((ext_vector_type(8))) short bf16x8;
typedef __attribute__((ext_vector_type(4))) float f32x4;

typedef void __attribute__((address_space(1)))* gas_ptr;
typedef void __attribute__((address_space(3)))* las_ptr;

__device__ __forceinline__ void gload16(const void* g, void* l) {
  __builtin_amdgcn_global_load_lds((gas_ptr)(void*)g, (las_ptr)l, 16, 0, 0);
}

#define VMCNT0 asm volatile("s_waitcnt vmcnt(0)" ::: "memory")
#define VMCNT2 asm volatile("s_waitcnt vmcnt(2)" ::: "memory")
#define VMCNT4 asm volatile("s_waitcnt vmcnt(4)" ::: "memory")
#define LGKM0  asm volatile("s_waitcnt lgkmcnt(0)" ::: "memory")
#define BARRIER asm volatile("s_barrier" ::: "memory")

__device__ __forceinline__ u16 f2bf(float f) {
  union { float f; uint32_t u; } a; a.f = f;
  uint32_t r = a.u + 0x7fffu + ((a.u >> 16) & 1u);
  return (u16)(r >> 16);
}
__device__ __forceinline__ float bf2f(u16 b) {
  union { uint32_t u; float f; } c; c.u = (uint32_t)b << 16; return c.f;
}
__device__ __forceinline__ uint32_t pack2(float a, float b) {
  return (uint32_t)f2bf(a) | ((uint32_t)f2bf(b) << 16);
}

// ---------------- fused prep kernel ----------------
// blocks [0,3072): x convert; [3072,6528): Wv convert; [6528,9984): Wc convert
// (identity layout at h0=0,Gi=12); [9984,13440): Wq/Wk transpose-convert.
__global__ void k_prep(const float* __restrict__ x, const float* __restrict__ wv,
                       const float* __restrict__ wc, const float* __restrict__ wq,
                       const float* __restrict__ wk,
                       u16* __restrict__ xb, u16* __restrict__ wvb,
                       u16* __restrict__ wcb, u16* __restrict__ wqT,
                       u16* __restrict__ wkT) {
  __shared__ float t[64][65];
  int b = blockIdx.x;
  if (b < 9984) {
    const float* s; u16* d; long base;
    if (b < 3072)      { s = x;  d = xb;  base = (long)b*2048; }
    else if (b < 6528) { s = wv; d = wvb; base = (long)(b-3072)*2048; }
    else               { s = wc; d = wcb; base = (long)(b-6528)*2048; }
    long i = base + (long)threadIdx.x*8;
    float4 a = *(const float4*)(s+i);
    float4 bb = *(const float4*)(s+i+4);
    uint4 o; o.x = pack2(a.x,a.y); o.y = pack2(a.z,a.w);
    o.z = pack2(bb.x,bb.y); o.w = pack2(bb.z,bb.w);
    *(uint4*)(d+i) = o;
  } else {
    int zz = b - 9984;
    int z = zz / 144, idx = zz - z*144;
    int d0 = (idx % 12)*64, e0 = (idx / 12)*64;
    const float* src = (z < 12) ? wq + (size_t)z*EMB*EMB : wk + (size_t)(z-12)*EMB*EMB;
    u16* dst = (z < 12) ? wqT + (size_t)z*EMB*EMB : wkT + (size_t)(z-12)*EMB*EMB;
    int tt = threadIdx.x;
    int el = tt & 63, db = tt >> 6;
    #pragma unroll
    for (int p = 0; p < 16; ++p) {
      int dl = p*4 + db;
      t[dl][el] = src[(size_t)(d0+dl)*EMB + e0 + el];
    }
    __syncthreads();
    int dl2 = tt & 63, eb = tt >> 6;
    #pragma unroll
    for (int p = 0; p < 16; ++p) {
      int e2 = p*4 + eb;
      dst[(size_t)(e0+e2)*EMB + d0 + dl2] = f2bf(t[dl2][e2]);
    }
  }
}

// a[g][e] = sum_d Wk[d][e]*bq[d]  — wave per output element
__global__ void k_mka(const u16* __restrict__ wkT, const float* __restrict__ bq,
                      float* __restrict__ a) {
  int g = blockIdx.y;
  int w = threadIdx.x >> 6, l = threadIdx.x & 63;
  int e = blockIdx.x*4 + w;
  const u16* row = wkT + (size_t)g*EMB*EMB + (size_t)e*EMB;
  const float* b = bq + (size_t)g*EMB;
  float s = 0.f;
  #pragma unroll
  for (int c = 0; c < 12; ++c) {
    int d = c*64 + l;
    s += bf2f(row[d]) * b[d];
  }
  s += __shfl_xor(s, 1); s += __shfl_xor(s, 2); s += __shfl_xor(s, 4);
  s += __shfl_xor(s, 8); s += __shfl_xor(s, 16); s += __shfl_xor(s, 32);
  if (l == 0) a[(size_t)g*EMB + e] = s;
}

// v[g][i] = sum_e xb[i][e]*a[g][e] — wave per row, single x pass, loop g in-reg
__global__ void k_mkv(const u16* __restrict__ xb, const float* __restrict__ a,
                      float* __restrict__ v) {
  int w = threadIdx.x >> 6, l = threadIdx.x & 63;
  int i = blockIdx.x*8 + w;
  const u16* xr = xb + (size_t)i*EMB;
  float xv[12];
  #pragma unroll
  for (int c = 0; c < 12; ++c) xv[c] = bf2f(xr[c*64 + l]);
  for (int g = 0; g < NHEAD; ++g) {
    const float* ag = a + (size_t)g*EMB;
    float s = 0.f;
    #pragma unroll
    for (int c = 0; c < 12; ++c) s += xv[c] * ag[c*64 + l];
    s += __shfl_xor(s, 1); s += __shfl_xor(s, 2); s += __shfl_xor(s, 4);
    s += __shfl_xor(s, 8); s += __shfl_xor(s, 16); s += __shfl_xor(s, 32);
    if (l == 0) v[(size_t)g*MROWS + i] = s;
  }
}

// ---------------- dual 256x256 NT GEMM (r4 structure; two configs per launch) ----------------
struct Gemm256Args {
  const u16* A; int lda;
  const u16* B; int ldb; int K;
  u16* Cb; long c_hs; int ldc;
  const float* bias; const float* bias2;
  int gsplit; int mode; int swap;
};

__global__ __launch_bounds__(512, 2) void k_gemm256d(Gemm256Args p0, Gemm256Args p1)
{
  __shared__ u16 lsA[2*16384];
  __shared__ u16 lsB[2*16384];

  const Gemm256Args P = blockIdx.z ? p1 : p0;
  int m0 = (P.swap ? blockIdx.y : blockIdx.x) * 256;
  int n0 = (P.swap ? blockIdx.x : blockIdx.y) * 256;
  int tid = threadIdx.x;
  int w = tid >> 6, l = tid & 63;
  int wr = w >> 2, wc = w & 3;

  const u16* gA = P.A + (size_t)(m0 + 32*w + (l>>3))*P.lda + (((l&7) ^ (l>>3)) << 3);
  const u16* gB = P.B + (size_t)(n0 + 32*w + (l>>3))*P.ldb + (((l&7) ^ (l>>3)) << 3);

#define STAGE256(t, buf) do { \
    int k0_ = (t)*64; \
    _Pragma("unroll") \
    for (int c_ = 0; c_ < 4; ++c_) \
      gload16(gA + (size_t)(c_*8)*P.lda + k0_, lsA + (buf)*16384 + (32*w + 8*c_)*64); \
    _Pragma("unroll") \
    for (int c_ = 0; c_ < 4; ++c_) \
      gload16(gB + (size_t)(c_*8)*P.ldb + k0_, lsB + (buf)*16384 + (32*w + 8*c_)*64); \
  } while(0)

  f32x4 acc[8][4];
  #pragma unroll
  for (int i = 0; i < 8; ++i)
    #pragma unroll
    for (int j = 0; j < 4; ++j) acc[i][j] = (f32x4)0.0f;

  int nt = P.K >> 6;
  STAGE256(0, 0);
  for (int t = 0; t < nt; ++t) {
    VMCNT0; BARRIER;
    if (t + 1 < nt) STAGE256(t+1, (t+1)&1);
    const u16* la = lsA + (t&1)*16384;
    const u16* lb = lsB + (t&1)*16384;
    #pragma unroll
    for (int ks = 0; ks < 2; ++ks) {
      int off = (((4*ks + (l>>4)) ^ (l&7)) << 3);
      bf16x8 af[8], bf_[4];
      #pragma unroll
      for (int fi = 0; fi < 8; ++fi)
        af[fi] = *(const bf16x8*)(la + (wr*128 + fi*16 + (l&15))*64 + off);
      #pragma unroll
      for (int fj = 0; fj < 4; ++fj)
        bf_[fj] = *(const bf16x8*)(lb + (wc*64 + fj*16 + (l&15))*64 + off);
      __builtin_amdgcn_s_setprio(1);
      #pragma unroll
      for (int fi = 0; fi < 8; ++fi)
        #pragma unroll
        for (int fj = 0; fj < 4; ++fj)
          acc[fi][fj] = __builtin_amdgcn_mfma_f32_16x16x32_bf16(af[fi], bf_[fj], acc[fi][fj], 0, 0, 0);
      __builtin_amdgcn_s_setprio(0);
    }
  }
#undef STAGE256

  if (P.mode == 0) {
    int s = n0 / 768;
    int dbase = n0 - s*768 + wc*64;
    const float* bsl = P.bias ? ((s < P.gsplit) ? P.bias + (size_t)s*768
                                                : P.bias2 + (size_t)(s - P.gsplit)*768)
                              : (const float*)0;
    u16* Cs = P.Cb + (size_t)s*P.c_hs;
    #pragma unroll
    for (int fj = 0; fj < 4; ++fj) {
      int dcol = dbase + fj*16 + (l&15);
      float bb = bsl ? bsl[dcol] : 0.f;
      #pragma unroll
      for (int fi = 0; fi < 8; ++fi) {
        #pragma unroll
        for (int r = 0; r < 4; ++r) {
          int row = m0 + wr*128 + fi*16 + (l>>4)*4 + r;
          Cs[(size_t)row*768 + dcol] = f2bf(acc[fi][fj][r] + bb);
        }
      }
    }
  } else {
    #pragma unroll
    for (int fi = 0; fi < 8; ++fi) {
      #pragma unroll
      for (int r = 0; r < 4; ++r) {
        int row = m0 + wr*128 + fi*16 + (l>>4)*4 + r;
        float bb = P.bias[row];
        #pragma unroll
        for (int fj = 0; fj < 4; ++fj) {
          int cbn = n0 + wc*64 + fj*16 + (l&15);
          P.Cb[(size_t)row*P.ldc + cbn] = f2bf(acc[fi][fj][r] + bb);
        }
      }
    }
  }
}

// ---------------- NT GEMM: 128x128 tile (Mt + output projection) ----------------
__global__ __launch_bounds__(256) void k_gemm(
    const u16* __restrict__ A, long a_hs, int lda,
    const u16* __restrict__ B, long b_hs, int ldb, int K,
    u16* Cb, float* Cf, long c_hs, int ldc,
    const float* __restrict__ bias, const float* __restrict__ bias2,
    long bias_hs, int gsplit, int mode, int swapxy)
{
  __shared__ u16 lsA[3*4096];
  __shared__ u16 lsB[3*4096];
  int g = blockIdx.z;
  const u16* Ag = A + (long)g*a_hs;
  const u16* Bg = B + (long)g*b_hs;
  int tm = swapxy ? blockIdx.y : blockIdx.x;
  int tn = swapxy ? blockIdx.x : blockIdx.y;
  int m0 = tm*128, n0 = tn*128;
  int tid = threadIdx.x;
  int w = tid >> 6, l = tid & 63;

  int srow = l >> 2;
  int scol = ((l & 3) ^ ((l >> 3) & 3)) * 8;
  const u16* ga0 = Ag + (long)(m0 + (2*w)*16   + srow)*lda + scol;
  const u16* ga1 = Ag + (long)(m0 + (2*w+1)*16 + srow)*lda + scol;
  const u16* gb0 = Bg + (long)(n0 + (2*w)*16   + srow)*ldb + scol;
  const u16* gb1 = Bg + (long)(n0 + (2*w+1)*16 + srow)*ldb + scol;

#define GSTAGE(k0, buf) do { \
    gload16(ga0 + (k0), lsA + (buf)*4096 + (2*w)*512); \
    gload16(ga1 + (k0), lsA + (buf)*4096 + (2*w+1)*512); \
    gload16(gb0 + (k0), lsB + (buf)*4096 + (2*w)*512); \
    gload16(gb1 + (k0), lsB + (buf)*4096 + (2*w+1)*512); \
  } while(0)

  f32x4 acc[4][4];
  #pragma unroll
  for (int i = 0; i < 4; ++i)
    #pragma unroll
    for (int j = 0; j < 4; ++j) acc[i][j] = (f32x4)0.0f;

  int wr = w >> 1, wc_ = w & 1;
  int frow = l & 15;
  int sp = (l >> 4) ^ ((frow >> 1) & 3);
  int aoff[4], boff[4];
  #pragma unroll
  for (int i = 0; i < 4; ++i) {
    aoff[i] = (wr*64 + i*16 + frow)*32 + sp*8;
    boff[i] = (wc_*64 + i*16 + frow)*32 + sp*8;
  }

  int nt = K >> 5;
  GSTAGE(0, 0);
  GSTAGE(32, 1);
  VMCNT4; BARRIER;
  int cur = 0;
  for (int t = 0; t < nt; ++t) {
    if (t + 2 < nt) {
      int nb = cur + 2; if (nb >= 3) nb -= 3;
      GSTAGE((t+2) << 5, nb);
    }
    const u16* la = lsA + cur*4096;
    const u16* lb = lsB + cur*4096;
    bf16x8 af[4], bfr[4];
    #pragma unroll
    for (int i = 0; i < 4; ++i) af[i] = *(const bf16x8*)(la + aoff[i]);
    #pragma unroll
    for (int j = 0; j < 4; ++j) bfr[j] = *(const bf16x8*)(lb + boff[j]);
    #pragma unroll
    for (int i = 0; i < 4; ++i)
      #pragma unroll
      for (int j = 0; j < 4; ++j)
        acc[i][j] = __builtin_amdgcn_mfma_f32_16x16x32_bf16(af[i], bfr[j], acc[i][j], 0, 0, 0);
    if (t + 2 < nt) { VMCNT4; } else { VMCNT0; }
    LGKM0; BARRIER;
    cur = (cur == 2) ? 0 : cur + 1;
  }
#undef GSTAGE

  u16* Cbg = Cb ? Cb + (long)g*c_hs : (u16*)0;
  const float* bsel = (g < gsplit) ? bias : bias2;
  long gi = (g < gsplit) ? g : g - gsplit;
  const float* bs = bsel ? bsel + gi*bias_hs : (const float*)0;
  int rl = (l >> 4)*4, cl = l & 15;
  #pragma unroll
  for (int i = 0; i < 4; ++i) {
    #pragma unroll
    for (int j = 0; j < 4; ++j) {
      int rb = m0 + wr*64 + i*16 + rl;
      int cb = n0 + wc_*64 + j*16 + cl;
      float cbv = 0.f;
      if ((mode == 0 || mode == 2) && bs) cbv = bs[cb];
      #pragma unroll
      for (int r = 0; r < 4; ++r) {
        int rr = rb + r;
        float v = acc[i][j][r];
        v += (mode == 1) ? bs[rr] : cbv;
        size_t idx = (size_t)rr*(size_t)ldc + cb;
        if (mode <= 1) Cbg[idx] = f2bf(v);
        else if (mode == 2) Cf[idx] = v;
        else Cf[idx] += v;
      }
    }
  }
}

// ---------------- flash attention (causal), QBLK=64, KBLK=64, 8 waves ----------------
// r10 version (measured best, 134 us): K-operand = xb shared across heads; bias vh.
__global__ __launch_bounds__(512, 2) void k_attn(
    const u16* __restrict__ qb, const u16* __restrict__ xkb,
    const u16* __restrict__ vtb, const float* __restrict__ vh,
    u16* __restrict__ hb, int ldh)
{
  __shared__ u16 kls[3*8192];
  __shared__ u16 vls[3*8192];
  __shared__ float s_t[64*68];
  __shared__ u16 p_t[64*64];
  __shared__ float e_s[64];

  int b = blockIdx.x;
  int xcd = b & 7, kk_ = b >> 3;
  int gn = xcd + 8*(kk_ >> 3), pair = kk_ & 7;
  int g = gn >> 3, n = gn & 7;

  const u16* Q  = qb  + (size_t)g*MROWS*EMB + (size_t)n*SEQ*EMB;
  const u16* Kp = xkb + (size_t)n*SEQ*EMB;
  const u16* Vt = vtb + (size_t)g*EMB*MROWS + (size_t)n*SEQ;
  const float* Vh = vh + (size_t)g*MROWS + (size_t)n*SEQ;
  u16* H = hb + (size_t)(n*SEQ)*ldh + (size_t)g*EMB;

  int tid = threadIdx.x;
  int w = tid >> 6, l = tid & 63;
  int qg = w >> 1;
  int cg = w & 1;
  int frow = l & 15;
  int fsw = frow & 7;
  int srow = tid >> 3;
  int sphys = tid & 7;
  int scol = ((sphys ^ (srow & 7)) << 3);

#define KSTAGE(base, pc, buf) do { \
    gload16((base) + (pc)*128,      kls + (buf)*8192 + w*512); \
    gload16((base) + (pc)*128 + 64, kls + (buf)*8192 + 4096 + w*512); \
  } while(0)
#define VSTAGE(vc, buf) do { \
    gload16(Vs + (size_t)((vc)*128)*MROWS,      vls + (buf)*8192 + w*512); \
    gload16(Vs + (size_t)((vc)*128 + 64)*MROWS, vls + (buf)*8192 + 4096 + w*512); \
  } while(0)

  for (int half = 0; half < 2; ++half) {
    int qt = half ? 15 - pair : pair;
    int q0 = qt * 64;
    int nt = qt + 1;

    f32x4 acc[6][4];
    #pragma unroll
    for (int i = 0; i < 6; ++i)
      #pragma unroll
      for (int j = 0; j < 4; ++j) acc[i][j] = (f32x4)0.0f;
    float m_reg = -1e30f, l_reg = 0.f;

    const u16* Qs = Q + (size_t)(q0 + srow)*EMB + scol;
    bf16x8 qreg[12][2];
    KSTAGE(Qs, 0, 0);
    KSTAGE(Qs, 1, 1);
    VMCNT2; BARRIER;
    #pragma unroll
    for (int pc = 0; pc < 6; ++pc) {
      if (pc < 4) KSTAGE(Qs, pc+2, (pc+2)%3);
      const u16* qb_ = kls + (pc%3)*8192;
      #pragma unroll
      for (int kk2 = 0; kk2 < 2; ++kk2)
        #pragma unroll
        for (int kkl = 0; kkl < 2; ++kkl)
          qreg[2*pc + kk2][kkl] = *(const bf16x8*)(qb_ + kk2*4096 + (qg*16 + frow)*64
                                                   + (((kkl*4 + (l>>4)) ^ fsw) << 3));
      if (pc < 4) { VMCNT2; } else if (pc == 4) { VMCNT0; }
      LGKM0; BARRIER;
    }

    for (int tt = 0; tt < nt; ++tt) {
      int t0 = tt*64;
      const u16* Ks = Kp + (size_t)(t0 + srow)*EMB + scol;
      const u16* Vs = Vt + (size_t)srow*MROWS + t0 + scol;
      float vv0 = Vh[t0 + cg*32 + frow];
      float vv1 = Vh[t0 + cg*32 + 16 + frow];
      if (tt == 0) { KSTAGE(Ks, 0, 0); KSTAGE(Ks, 1, 1); }
      VMCNT2; BARRIER;

      f32x4 sacc[2]; sacc[0] = (f32x4)0.0f; sacc[1] = (f32x4)0.0f;
      #pragma unroll
      for (int c = 0; c < 6; ++c) {
        if (c < 4)       KSTAGE(Ks, c+2, (c+2)%3);
        else if (c == 4) VSTAGE(0, 0);
        else             VSTAGE(1, 1);
        const u16* kb_ = kls + (c%3)*8192;
        __builtin_amdgcn_s_setprio(1);
        #pragma unroll
        for (int kk2 = 0; kk2 < 2; ++kk2) {
          #pragma unroll
          for (int kkl = 0; kkl < 2; ++kkl) {
            int so = ((kkl*4 + (l>>4)) ^ fsw) << 3;
            bf16x8 aq = qreg[2*c + kk2][kkl];
            #pragma unroll
            for (int cc = 0; cc < 2; ++cc) {
              bf16x8 bk_ = *(const bf16x8*)(kb_ + kk2*4096 + ((cg*2 + cc)*16 + frow)*64 + so);
              sacc[cc] = __builtin_amdgcn_mfma_f32_16x16x32_bf16(aq, bk_, sacc[cc], 0, 0, 0);
            }
          }
        }
        __builtin_amdgcn_s_setprio(0);
        if (c < 5) { VMCNT2; LGKM0; BARRIER; }
      }

      #pragma unroll
      for (int r = 0; r < 4; ++r) {
        s_t[(qg*16 + (l>>4)*4 + r)*68 + cg*32 + frow]      = (sacc[0][r] + vv0)*SCALE_S;
        s_t[(qg*16 + (l>>4)*4 + r)*68 + cg*32 + 16 + frow] = (sacc[1][r] + vv1)*SCALE_S;
      }
      LGKM0; BARRIER;
      {
        int qglob = q0 + srow;
        int cbase = t0 + sphys*8;
        float v[8]; float mx = -1e30f;
        #pragma unroll
        for (int j = 0; j < 8; ++j) {
          float s = s_t[srow*68 + sphys*8 + j];
          if (cbase + j > qglob) s = -1e30f;
          v[j] = s; mx = fmaxf(mx, s);
        }
        mx = fmaxf(mx, __shfl_xor(mx, 1));
        mx = fmaxf(mx, __shfl_xor(mx, 2));
        mx = fmaxf(mx, __shfl_xor(mx, 4));
        float mn = fmaxf(m_reg, mx);
        float esc = __expf(m_reg - mn);
        float ps = 0.f; u16 pk[8];
        #pragma unroll
        for (int j = 0; j < 8; ++j) { float p = __expf(v[j] - mn); ps += p; pk[j] = f2bf(p); }
        ps += __shfl_xor(ps, 1); ps += __shfl_xor(ps, 2); ps += __shfl_xor(ps, 4);
        l_reg = l_reg*esc + ps; m_reg = mn;
        if (sphys == 0) e_s[srow] = esc;
        uint4 pv;
        pv.x = (uint32_t)pk[0] | ((uint32_t)pk[1] << 16);
        pv.y = (uint32_t)pk[2] | ((uint32_t)pk[3] << 16);
        pv.z = (uint32_t)pk[4] | ((uint32_t)pk[5] << 16);
        pv.w = (uint32_t)pk[6] | ((uint32_t)pk[7] << 16);
        *(uint4*)(p_t + srow*64 + ((sphys ^ (srow & 7)) << 3)) = pv;
      }
      VMCNT2; LGKM0; BARRIER;
      float er[4];
      #pragma unroll
      for (int r = 0; r < 4; ++r) er[r] = e_s[qg*16 + (l>>4)*4 + r];
      #pragma unroll
      for (int i = 0; i < 6; ++i)
        #pragma unroll
        for (int j = 0; j < 4; ++j)
          #pragma unroll
          for (int r = 0; r < 4; ++r) acc[i][j][r] *= er[r];
      bf16x8 pa[2];
      #pragma unroll
      for (int kk = 0; kk < 2; ++kk)
        pa[kk] = *(const bf16x8*)(p_t + (qg*16 + frow)*64 + (((kk*4 + (l>>4)) ^ fsw) << 3));
      bool stage_next = (tt + 1 < nt);
      const u16* Ks2 = Kp + (size_t)(t0 + 64 + srow)*EMB + scol;
      #pragma unroll
      for (int c = 0; c < 6; ++c) {
        if (c < 4)            VSTAGE(c+2, (c+2)%3);
        else if (stage_next)  { if (c == 4) KSTAGE(Ks2, 0, 0); else KSTAGE(Ks2, 1, 1); }
        const u16* vb_ = vls + (c%3)*8192;
        __builtin_amdgcn_s_setprio(1);
        #pragma unroll
        for (int cf = 0; cf < 4; ++cf) {
          #pragma unroll
          for (int kk = 0; kk < 2; ++kk) {
            bf16x8 vbf = *(const bf16x8*)(vb_ + (cg*64 + cf*16 + frow)*64 + (((kk*4 + (l>>4)) ^ fsw) << 3));
            acc[c][cf] = __builtin_amdgcn_mfma_f32_16x16x32_bf16(pa[kk], vbf, acc[c][cf], 0, 0, 0);
          }
        }
        __builtin_amdgcn_s_setprio(0);
        if (c < 4)      { VMCNT2; LGKM0; BARRIER; }
        else if (c == 4){ if (stage_next) { VMCNT2; } else { VMCNT0; } LGKM0; BARRIER; }
      }
    } // tt
    if (sphys == 0) e_s[srow] = l_reg;
    LGKM0; BARRIER;
    float linv[4];
    #pragma unroll
    for (int r = 0; r < 4; ++r) linv[r] = 1.0f / e_s[qg*16 + (l>>4)*4 + r];
    #pragma unroll
    for (int i = 0; i < 6; ++i)
      #pragma unroll
      for (int j = 0; j < 4; ++j) {
        int col = i*128 + cg*64 + j*16 + (l & 15);
        #pragma unroll
        for (int r = 0; r < 4; ++r) {
          int row = q0 + qg*16 + (l>>4)*4 + r;
          H[(size_t)row*ldh + col] = f2bf(acc[i][j][r]*linv[r]);
        }
      }
    BARRIER;
  } // half
#undef KSTAGE
#undef VSTAGE
}

// ---------------- host ----------------
extern "C" void kernel_launch(void* const* d_in, const int* in_sizes, int n_in,
                              void* d_out, int out_size, void* d_ws, size_t ws_size,
                              hipStream_t stream) {
  const float* x  = (const float*)d_in[0];
  const float* Wq = (const float*)d_in[1];
  const float* bq = (const float*)d_in[2];
  const float* Wk = (const float*)d_in[3];
  const float* bv = (const float*)d_in[6];
  const float* Wv = (const float*)d_in[5];
  const float* Wc = (const float*)d_in[7];
  const float* bc = (const float*)d_in[8];
  float* out = (float*)d_out;
  // bk enters only through a row-constant softmax term -> cancels

  const size_t XB  = (size_t)MROWS*EMB*sizeof(u16);
  const size_t WHB = (size_t)EMB*EMB*sizeof(u16);
  const size_t VHB = (size_t)MROWS*sizeof(float);
  const size_t AB  = (size_t)EMB*sizeof(float);
  const size_t fixed = XB + 36*WHB + 12*(VHB + AB) + 8192;
  int G = 4;
  while (G > 2 && fixed + (size_t)G*3*XB > ws_size) --G;

  char* ws = (char*)d_ws;
  u16* xb  = (u16*)ws;  ws += XB;
  u16* wvb = (u16*)ws;  ws += 12*WHB;
  u16* wcb = (u16*)ws;  ws += 12*WHB;
  u16* mtb = (u16*)ws;  ws += 12*WHB;
  float* vh = (float*)ws; ws += 12*VHB;
  float* ab = (float*)ws; ws += 12*AB;
  u16* yb  = (u16*)ws;  ws += (size_t)G*XB;
  u16* vtb = (u16*)ws;  ws += (size_t)G*XB;
  u16* hbf = (u16*)ws;  ws += (size_t)G*XB;
  // one-time transposed-weight scratch aliases hbf (wqT) and vtb (wkT)
  u16* wqT = hbf;
  u16* wkT = vtb;

  // ---- one-time prep (all 12 heads): fused converts, Mt, bias terms ----
  k_prep<<<dim3(13440), dim3(256), 0, stream>>>(
      x, Wv, Wc, Wq, Wk, xb, wvb, wcb, wqT, wkT);
  k_gemm<<<dim3(6, 6, 12), dim3(256), 0, stream>>>(
      wkT, (long)EMB*EMB, EMB, wqT, (long)EMB*EMB, EMB, EMB,
      mtb, (float*)0, (long)EMB*EMB, EMB,
      (const float*)0, (const float*)0, 0L, 9999, 0, 0);
  k_mka<<<dim3(192, 12), dim3(256), 0, stream>>>(wkT, bq, ab);
  k_mkv<<<dim3(1024), dim3(512), 0, stream>>>(xb, ab, vh);

  for (int h0 = 0; h0 < NHEAD; h0 += G) {
    int Gi = (G < NHEAD - h0) ? G : (NHEAD - h0);
    // fused launch: z=0 -> y = x*Mt^T (sliced bf16), z=1 -> Vt = Wv*x^T + bv
    Gemm256Args ay = { xb, EMB, mtb + (size_t)h0*EMB*EMB, EMB, EMB,
                       yb, (long)MROWS*EMB, 768,
                       (const float*)0, (const float*)0, Gi, 0, 0 };
    Gemm256Args av = { wvb + (size_t)h0*EMB*EMB, EMB, xb, EMB, EMB,
                       vtb, 0L, MROWS,
                       bv + (size_t)h0*EMB, (const float*)0, 9999, 1, 1 };
    k_gemm256d<<<dim3(32, 3*Gi, 2), dim3(512), 0, stream>>>(ay, av);
    // flash attention (K = xb) -> hbf [8192, Gi*768]
    k_attn<<<dim3(8*NBAT*Gi), dim3(512), 0, stream>>>(
        yb, xb, vtb, vh + (size_t)h0*MROWS, hbf, Gi*EMB);
    // out += heads_group * Wc_group^T (+bc on first group)
    k_gemm<<<dim3(64, 6, 1), dim3(256), 0, stream>>>(
        hbf, 0L, Gi*EMB, wcb + (size_t)h0*EMB, 0L, NHEAD*EMB, Gi*EMB,
        (u16*)0, out, 0L, EMB,
        (h0 == 0 ? bc : (const float*)0), (const float*)0, 0L, 9999,
        (h0 == 0 ? 2 : 3), 0);
  }
}